// Round 2
// baseline (6734.850 us; speedup 1.0000x reference)
//
#include <hip/hip_runtime.h>
#include <math.h>

#define EPS 1e-5f

__device__ __forceinline__ float sigf(float x){ return 1.0f/(1.0f + __expf(-x)); }
__device__ __forceinline__ float tanhfast(float x){ return 2.0f/(1.0f + __expf(-2.0f*x)) - 1.0f; }

// ---------------- conv1 + bn1 stats (per branch) ----------------
__global__ __launch_bounds__(256) void k_conv1_stats(
    const float* __restrict__ x, const float* __restrict__ w1,
    const float* __restrict__ b1, float* __restrict__ acc)
{
  int n = blockIdx.x*256 + threadIdx.x;     // (b,t), 524288 total
  int b = n >> 7, t = n & 127;
  const float* xb = x + b*1024 + t;
  float xv[8];
#pragma unroll
  for (int ch=0; ch<8; ++ch) xv[ch] = xb[ch*128];
  int lane = threadIdx.x & 63;
#pragma unroll
  for (int f=0; f<16; ++f) {
    float v = b1[f];
#pragma unroll
    for (int ch=0; ch<8; ++ch) v = fmaf(xv[ch], w1[f*8+ch], v);
    float v2 = v*v;
#pragma unroll
    for (int d=32; d>0; d>>=1) { v += __shfl_down(v,d); v2 += __shfl_down(v2,d); }
    if (lane==0) { atomicAdd(&acc[2*f], v); atomicAdd(&acc[2*f+1], v2); }
  }
}

// ---------------- generic BN finalize: scale/shift from sum/sumsq ----------------
__global__ void k_finalize_bn(const float* __restrict__ acc, const float* __restrict__ g,
                              const float* __restrict__ b, float* __restrict__ prm,
                              int C, float invN)
{
  int i = blockIdx.x*blockDim.x + threadIdx.x;
  if (i < C) {
    float m = acc[2*i]*invN;
    float v = acc[2*i+1]*invN - m*m;
    float sc = g[i] / sqrtf(v + EPS);
    prm[2*i]   = sc;
    prm[2*i+1] = fmaf(-m, sc, b[i]);
  }
}

// ---------------- conv1(recompute)+bn1+prelu -> conv2 -> raw out + bn2 stats ----------------
__global__ __launch_bounds__(256) void k_conv2(
    const float* __restrict__ x,
    const float* __restrict__ w1, const float* __restrict__ b1,
    const float* __restrict__ prm1, const float* __restrict__ prelu1,
    const float* __restrict__ w2, const float* __restrict__ b2,
    float* __restrict__ sig, float* __restrict__ acc2)
{
  __shared__ float xb[1024];
  __shared__ float h1p[16*136];
  __shared__ float w2s[32*16*12];
  __shared__ float w1s[128];
  __shared__ float p1s[32];
  int tid = threadIdx.x; int b = blockIdx.x;
  *(float4*)&xb[tid*4] = *(const float4*)&x[b*1024 + tid*4];
  for (int i=tid; i<5120; i+=256) { int ff=i/10, k=i-ff*10; w2s[ff*12+k] = w2[i]; }
  if (tid<128) w1s[tid] = w1[tid];
  if (tid<32)  p1s[tid] = prm1[tid];
  float a1 = prelu1[0];
  __syncthreads();
#pragma unroll
  for (int r=0; r<8; ++r) {
    int o = tid + 256*r; int f = o>>7, t = o&127;
    float v = b1[f];
#pragma unroll
    for (int ch=0; ch<8; ++ch) v = fmaf(xb[ch*128+t], w1s[f*8+ch], v);
    v = fmaf(v, p1s[2*f], p1s[2*f+1]);
    v = (v>=0.f) ? v : a1*v;
    h1p[f*136 + t] = v;
  }
  __syncthreads();
  int f2 = tid>>3, wb = (tid&7)*8;
  float acc[8];
  float bb = b2[f2];
#pragma unroll
  for (int j=0;j<8;++j) acc[j]=bb;
  for (int f1=0; f1<16; ++f1) {
    const float* hrow = &h1p[f1*136 + 2*wb];
    float hw[24];
#pragma unroll
    for (int m=0;m<6;++m) *(float4*)&hw[m*4] = *(const float4*)&hrow[m*4];
    const float* wr = &w2s[(f2*16+f1)*12];
    float wk[10];
    *(float4*)&wk[0] = *(const float4*)&wr[0];
    *(float4*)&wk[4] = *(const float4*)&wr[4];
    wk[8]=wr[8]; wk[9]=wr[9];
#pragma unroll
    for (int j=0;j<8;++j)
#pragma unroll
      for (int k=0;k<10;++k) acc[j] = fmaf(hw[2*j+k], wk[k], acc[j]);
  }
  float s=0.f, q=0.f;
#pragma unroll
  for (int j=0;j<8;++j) {
    int w = wb+j;
    if (w < 60) { sig[b*1920 + f2*60 + w] = acc[j]; s += acc[j]; q = fmaf(acc[j],acc[j],q); }
  }
  s += __shfl_down(s,4,8); q += __shfl_down(q,4,8);
  s += __shfl_down(s,2,8); q += __shfl_down(q,2,8);
  s += __shfl_down(s,1,8); q += __shfl_down(q,1,8);
  if ((tid&7)==0) { atomicAdd(&acc2[2*f2], s); atomicAdd(&acc2[2*f2+1], q); }
}

// ---------------- cosine table for 60-pt real-FFT ----------------
__global__ void k_costab(float* __restrict__ ct)
{
  int i = blockIdx.x*256 + threadIdx.x;
  if (i < 3600) {
    int k = i/60, n = i - k*60;
    int m = (k*n) % 60;
    ct[i] = cosf(0.104719755119659775f * (float)m);  // 2*pi/60
  }
}

// ---------------- bn2-apply + prelu (in-place sig) + 60-pt cos transform -> fft ----------------
__global__ __launch_bounds__(256) void k_sigfft(
    float* __restrict__ sig, float* __restrict__ fft,
    const float* __restrict__ prm2, const float* __restrict__ prelu2,
    const float* __restrict__ ctab)
{
  __shared__ float ct[3600];
  __shared__ float rowb[4*60];
  int tid = threadIdx.x;
  for (int i=tid; i<3600; i+=256) ct[i] = ctab[i];
  int r4 = tid>>6, lane = tid&63;
  int row = blockIdx.x*4 + r4;        // (b,c), 131072 rows
  int c = row & 31;
  float a2 = prelu2[0];
  float sc = prm2[2*c], sh = prm2[2*c+1];
  size_t base = (size_t)row*60;
  if (lane < 60) {
    float v = fmaf(sig[base+lane], sc, sh);
    v = (v>=0.f) ? v : a2*v;
    rowb[r4*60+lane] = v;
    sig[base+lane] = v;
  }
  __syncthreads();
  if (lane < 60) {
    float s = 0.f;
    const float* rb = &rowb[r4*60];
#pragma unroll 6
    for (int n=0; n<60; ++n) s = fmaf(rb[n], ct[n*60+lane], s);
    fft[base+lane] = s;
  }
}

// ---------------- bidirectional LSTM; lane=sample, wave=hidden pair ----------------
// grid (64 sample-blocks, 2 dirs, nbranch), 1024 threads (16 waves)
__global__ __launch_bounds__(1024) void k_lstm(
    const float* __restrict__ inA, const float* __restrict__ inB,
    float* __restrict__ outA, float* __restrict__ outB,
    const float* __restrict__ wihf, const float* __restrict__ whhf,
    const float* __restrict__ bihf, const float* __restrict__ bhhf,
    const float* __restrict__ wihr, const float* __restrict__ whhr,
    const float* __restrict__ bihr, const float* __restrict__ bhhr,
    int accmode)
{
  __shared__ float A[64*68];          // [sample][k] : k<32 = x_t, k in [32,64) = h
  const int tid  = threadIdx.x;
  const int lane = tid & 63;
  const int wid  = __builtin_amdgcn_readfirstlane(tid >> 6);  // wave-uniform hidden group
  const int sb   = blockIdx.x * 64;
  const int dir  = blockIdx.y;
  const float* in  = blockIdx.z ? inB : inA;
  float*       out = blockIdx.z ? outB : outA;
  const float* wih = dir ? wihr : wihf;
  const float* whh = dir ? whhr : whhf;
  const float* bih = dir ? bihr : bihf;
  const float* bhh = dir ? bhhr : bhhf;
  const int j0  = wid*2;
  const int col = dir ? 32 : 0;

  float bias[8];
#pragma unroll
  for (int gg=0; gg<4; ++gg) {
    bias[gg]   = bih[j0+32*gg]   + bhh[j0+32*gg];
    bias[4+gg] = bih[j0+32*gg+1] + bhh[j0+32*gg+1];
  }
  // zero h region (each wave zeroes its own 2 columns for all 64 samples)
  *(float2*)&A[lane*68 + 32 + j0] = make_float2(0.f, 0.f);
  // stage X for first step
  {
    const int t0 = dir ? 59 : 0;
    const int e = tid*2;
    float2 xv = *(const float2*)(in + (size_t)t0*131072 + (size_t)sb*32 + e);
    *(float2*)&A[(e>>5)*68 + (e&31)] = xv;
  }
  float c0 = 0.f, c1 = 0.f;
  __syncthreads();

  for (int q=0; q<60; ++q) {
    const int t = dir ? (59-q) : q;
    float2 xnext = make_float2(0.f, 0.f);
    if (q < 59) {
      const int tn = dir ? (58-q) : (q+1);
      xnext = *(const float2*)(in + (size_t)tn*131072 + (size_t)sb*32 + tid*2);
    }
    float acc[8];
#pragma unroll
    for (int r=0;r<8;++r) acc[r] = bias[r];
    const float* Ax = &A[lane*68];
#pragma unroll
    for (int k=0; k<32; k+=4) {
      const float4 av = *(const float4*)(Ax + k);
#pragma unroll
      for (int gg=0; gg<4; ++gg) {
        const float4 w0 = *(const float4*)(wih + (j0+32*gg)*32 + k);
        const float4 w1 = *(const float4*)(wih + (j0+32*gg+1)*32 + k);
        acc[gg]   = fmaf(av.w,w0.w, fmaf(av.z,w0.z, fmaf(av.y,w0.y, fmaf(av.x,w0.x, acc[gg]))));
        acc[4+gg] = fmaf(av.w,w1.w, fmaf(av.z,w1.z, fmaf(av.y,w1.y, fmaf(av.x,w1.x, acc[4+gg]))));
      }
    }
#pragma unroll
    for (int k=0; k<32; k+=4) {
      const float4 av = *(const float4*)(Ax + 32 + k);
#pragma unroll
      for (int gg=0; gg<4; ++gg) {
        const float4 w0 = *(const float4*)(whh + (j0+32*gg)*32 + k);
        const float4 w1 = *(const float4*)(whh + (j0+32*gg+1)*32 + k);
        acc[gg]   = fmaf(av.w,w0.w, fmaf(av.z,w0.z, fmaf(av.y,w0.y, fmaf(av.x,w0.x, acc[gg]))));
        acc[4+gg] = fmaf(av.w,w1.w, fmaf(av.z,w1.z, fmaf(av.y,w1.y, fmaf(av.x,w1.x, acc[4+gg]))));
      }
    }
    // i=acc[0], f=acc[1], g=acc[2], o=acc[3] (and 4..7 for j0+1)
    float c0n = sigf(acc[1])*c0 + sigf(acc[0])*tanhfast(acc[2]);
    float h0n = sigf(acc[3])*tanhfast(c0n);
    c0 = c0n;
    float c1n = sigf(acc[5])*c1 + sigf(acc[4])*tanhfast(acc[6]);
    float h1n = sigf(acc[7])*tanhfast(c1n);
    c1 = c1n;
    __syncthreads();                                  // everyone done reading old A
    *(float2*)&A[lane*68 + 32 + j0] = make_float2(h0n, h1n);
    if (q < 59) {
      const int e = tid*2;
      *(float2*)&A[(e>>5)*68 + (e&31)] = xnext;
    }
    __syncthreads();                                  // new h + next X visible
    // coalesced copy-out of this step's h tile
    {
      const int e = tid*2;
      const int s = e>>5, j = e&31;
      float2 hv = *(const float2*)&A[s*68 + 32 + j];
      float* dst = out + (size_t)t*262144 + (size_t)(sb+s)*64 + col + j;
      if (accmode) { hv.x += dst[0]; hv.y += dst[1]; }
      *(float2*)dst = hv;
    }
  }
}

// ---------------- bnf stats over (4096 rows x 3840 features) ----------------
__global__ __launch_bounds__(256) void k_bnfstats(const float* __restrict__ rb, float* __restrict__ acc)
{
  int col = blockIdx.x*256 + threadIdx.x;            // 0..3839
  size_t r0 = (size_t)blockIdx.y*256;
  const float* p = rb + r0*3840 + col;
  float s=0.f, q=0.f;
  for (int r=0; r<256; ++r) { float v = p[(size_t)r*3840]; s += v; q = fmaf(v,v,q); }
  atomicAdd(&acc[2*col], s); atomicAdd(&acc[2*col+1], q);
}

// ---------------- bn1d-apply + correlation + final 5-tap conv ----------------
__global__ __launch_bounds__(64) void k_corr(
    const float* __restrict__ ra, const float* __restrict__ rb,
    const float* __restrict__ pfa, const float* __restrict__ pfb,
    const float* __restrict__ cw, const float* __restrict__ cb,
    float* __restrict__ dout)
{
  __shared__ float sxt[12], sxx[12], stt[12], cv[12];
  int lane = threadIdx.x; int r = blockIdx.x;
  if (lane < 12) { sxt[lane]=0.f; sxx[lane]=0.f; stt[lane]=0.f; }
  __syncthreads();
  const float* pa = ra + (size_t)r*3840;
  const float* pb = rb + (size_t)r*3840;
  float xt0=0,xx0=0,tt0=0, xt1=0,xx1=0,tt1=0, xt2=0,xx2=0,tt2=0;
  for (int i=0; i<60; i+=3) {
    { int fe = lane + 64*i;
      float a = fmaf(pa[fe], pfa[2*fe], pfa[2*fe+1]);
      float b = fmaf(pb[fe], pfb[2*fe], pfb[2*fe+1]);
      xt0 = fmaf(a,b,xt0); xx0 = fmaf(a,a,xx0); tt0 = fmaf(b,b,tt0); }
    { int fe = lane + 64*(i+1);
      float a = fmaf(pa[fe], pfa[2*fe], pfa[2*fe+1]);
      float b = fmaf(pb[fe], pfb[2*fe], pfb[2*fe+1]);
      xt1 = fmaf(a,b,xt1); xx1 = fmaf(a,a,xx1); tt1 = fmaf(b,b,tt1); }
    { int fe = lane + 64*(i+2);
      float a = fmaf(pa[fe], pfa[2*fe], pfa[2*fe+1]);
      float b = fmaf(pb[fe], pfb[2*fe], pfb[2*fe+1]);
      xt2 = fmaf(a,b,xt2); xx2 = fmaf(a,a,xx2); tt2 = fmaf(b,b,tt2); }
  }
  int c0 = lane % 12;
  int c1 = (c0+4) % 12;
  int c2 = (c0+8) % 12;
  atomicAdd(&sxt[c0], xt0); atomicAdd(&sxx[c0], xx0); atomicAdd(&stt[c0], tt0);
  atomicAdd(&sxt[c1], xt1); atomicAdd(&sxx[c1], xx1); atomicAdd(&stt[c1], tt1);
  atomicAdd(&sxt[c2], xt2); atomicAdd(&sxx[c2], xx2); atomicAdd(&stt[c2], tt2);
  __syncthreads();
  if (lane < 12) {
    float corr = sxt[lane] / sqrtf(stt[lane]) / sqrtf(sxx[lane]);
    cv[lane] = corr;
    dout[49152 + r*12 + lane] = corr;
  }
  __syncthreads();
  if (lane < 12) {
    float o = cb[0];
#pragma unroll
    for (int k=0; k<5; ++k) { int j = lane + k - 2; if (j>=0 && j<12) o = fmaf(cv[j], cw[k], o); }
    dout[r*12 + lane] = o;
  }
}

// ---------------- host ----------------
extern "C" void kernel_launch(void* const* d_in, const int* in_sizes, int n_in,
                              void* d_out, int out_size, void* d_ws, size_t ws_size,
                              hipStream_t stream)
{
  const float* x    = (const float*)d_in[0];
  const float* tpl  = (const float*)d_in[1];
  const float* w1   = (const float*)d_in[2];
  const float* b1   = (const float*)d_in[3];
  const float* g1   = (const float*)d_in[4];
  const float* bb1  = (const float*)d_in[5];
  const float* p1   = (const float*)d_in[6];
  const float* w2   = (const float*)d_in[7];
  const float* b2   = (const float*)d_in[8];
  const float* g2   = (const float*)d_in[9];
  const float* bb2  = (const float*)d_in[10];
  const float* p2   = (const float*)d_in[11];
  const float* wihf = (const float*)d_in[12];
  const float* whhf = (const float*)d_in[13];
  const float* bihf = (const float*)d_in[14];
  const float* bhhf = (const float*)d_in[15];
  const float* wihr = (const float*)d_in[16];
  const float* whhr = (const float*)d_in[17];
  const float* bihr = (const float*)d_in[18];
  const float* bhhr = (const float*)d_in[19];
  const float* gf   = (const float*)d_in[20];
  const float* bf   = (const float*)d_in[21];
  const float* cw   = (const float*)d_in[22];
  const float* cb   = (const float*)d_in[23];
  float* W   = (float*)d_ws;
  float* out = (float*)d_out;

  // small scratch (float offsets)
  constexpr size_t ACC1A=0, ACC1B=32, PRM1A=64, PRM1B=96;
  constexpr size_t ACC2A=128, ACC2B=192, PRM2A=256, PRM2B=320;
  constexpr size_t ACCFA=512, ACCFB=8192, PRMFA=15872, PRMFB=23552, CTAB=31232;
  constexpr size_t SIGSZ = 7864320, RSZ = 15728640;
  constexpr size_t BIG0 = 65536;
  // fast layout: sigA | fftA | sigB | fftB | rbufA | rbufB   (252 MB)
  constexpr size_t F_SIGA=BIG0, F_FFTA=F_SIGA+SIGSZ, F_SIGB=F_FFTA+SIGSZ, F_FFTB=F_SIGB+SIGSZ;
  constexpr size_t F_RBUFA=F_FFTB+SIGSZ, F_RBUFB=F_RBUFA+RSZ;
  constexpr size_t F_TOTAL=(F_RBUFB+RSZ)*sizeof(float);
  // sequential layout: sig | fft | rbufA | rbufB   (189 MB)
  constexpr size_t S_SIG=BIG0, S_FFT=S_SIG+SIGSZ, S_RBUFA=S_FFT+SIGSZ, S_RBUFB=S_RBUFA+RSZ;

  const bool fast = ws_size >= F_TOTAL;

  hipMemsetAsync(W, 0, 65536, stream);               // zero all stat accumulators
  k_costab<<<15,256,0,stream>>>(W+CTAB);

  for (int br=0; br<2; ++br) {
    const float* xin  = br ? tpl : x;
    float* acc1 = W + (br ? ACC1B : ACC1A);
    float* prm1 = W + (br ? PRM1B : PRM1A);
    float* acc2 = W + (br ? ACC2B : ACC2A);
    float* prm2 = W + (br ? PRM2B : PRM2A);
    float* sig  = W + (fast ? (br ? F_SIGB : F_SIGA) : S_SIG);
    float* fft  = W + (fast ? (br ? F_FFTB : F_FFTA) : S_FFT);
    float* rbuf = W + (fast ? (br ? F_RBUFB : F_RBUFA) : (br ? S_RBUFB : S_RBUFA));
    k_conv1_stats<<<2048,256,0,stream>>>(xin, w1, b1, acc1);
    k_finalize_bn<<<1,32,0,stream>>>(acc1, g1, bb1, prm1, 16, 1.f/524288.f);
    k_conv2<<<4096,256,0,stream>>>(xin, w1, b1, prm1, p1, w2, b2, sig, acc2);
    k_finalize_bn<<<1,32,0,stream>>>(acc2, g2, bb2, prm2, 32, 1.f/245760.f);
    k_sigfft<<<32768,256,0,stream>>>(sig, fft, prm2, p2, W+CTAB);
    if (!fast) {
      // half-occupancy LSTM per branch (memory-constrained path)
      k_lstm<<<dim3(64,2,1),1024,0,stream>>>(sig, sig, rbuf, rbuf,
                                             wihf,whhf,bihf,bhhf, wihr,whhr,bihr,bhhr, 0);
      k_lstm<<<dim3(64,2,1),1024,0,stream>>>(fft, fft, rbuf, rbuf,
                                             wihf,whhf,bihf,bhhf, wihr,whhr,bihr,bhhr, 1);
    }
  }

  float* rbufA = W + (fast ? F_RBUFA : S_RBUFA);
  float* rbufB = W + (fast ? F_RBUFB : S_RBUFB);

  if (fast) {
    k_lstm<<<dim3(64,2,2),1024,0,stream>>>(W+F_SIGA, W+F_SIGB, rbufA, rbufB,
                                           wihf,whhf,bihf,bhhf, wihr,whhr,bihr,bhhr, 0);
    k_lstm<<<dim3(64,2,2),1024,0,stream>>>(W+F_FFTA, W+F_FFTB, rbufA, rbufB,
                                           wihf,whhf,bihf,bhhf, wihr,whhr,bihr,bhhr, 1);
  }

  k_bnfstats<<<dim3(15,16),256,0,stream>>>(rbufA, W+ACCFA);
  k_bnfstats<<<dim3(15,16),256,0,stream>>>(rbufB, W+ACCFB);
  k_finalize_bn<<<15,256,0,stream>>>(W+ACCFA, gf, bf, W+PRMFA, 3840, 1.f/4096.f);
  k_finalize_bn<<<15,256,0,stream>>>(W+ACCFB, gf, bf, W+PRMFB, 3840, 1.f/4096.f);

  k_corr<<<4096,64,0,stream>>>(rbufA, rbufB, W+PRMFA, W+PRMFB, cw, cb, out);
}

// Round 3
// 1923.530 us; speedup vs baseline: 3.5013x; 3.5013x over previous
//
#include <hip/hip_runtime.h>
#include <math.h>

#define EPS 1e-5f

__device__ __forceinline__ float sigf(float x){ return 1.0f/(1.0f + __expf(-x)); }
__device__ __forceinline__ float tanhfast(float x){ return 2.0f/(1.0f + __expf(-2.0f*x)) - 1.0f; }

// ---------------- conv1 + bn1 partial stats: 256 blocks, register+LDS reduce ----------------
__global__ __launch_bounds__(256) void k_conv1_stats(
    const float* __restrict__ x, const float* __restrict__ w1,
    const float* __restrict__ b1, float* __restrict__ part)
{
  __shared__ float red[4][32];
  float s[16], q[16];
#pragma unroll
  for (int f=0; f<16; ++f) { s[f]=0.f; q[f]=0.f; }
  float w1r[128];
#pragma unroll
  for (int i=0; i<128; ++i) w1r[i] = w1[i];
  float b1r[16];
#pragma unroll
  for (int f=0; f<16; ++f) b1r[f] = b1[f];
  const int tid = threadIdx.x;
  for (int iter=0; iter<8; ++iter) {
    int n = blockIdx.x*2048 + iter*256 + tid;      // (b,t), 524288 total
    int b = n >> 7, t = n & 127;
    const float* xb = x + b*1024 + t;
    float xv[8];
#pragma unroll
    for (int ch=0; ch<8; ++ch) xv[ch] = xb[ch*128];
#pragma unroll
    for (int f=0; f<16; ++f) {
      float v = b1r[f];
#pragma unroll
      for (int ch=0; ch<8; ++ch) v = fmaf(xv[ch], w1r[f*8+ch], v);
      s[f] += v; q[f] = fmaf(v,v,q[f]);
    }
  }
  // wave reduce all 32 accumulators
#pragma unroll
  for (int f=0; f<16; ++f) {
#pragma unroll
    for (int d=32; d>0; d>>=1) { s[f] += __shfl_down(s[f],d); q[f] += __shfl_down(q[f],d); }
  }
  const int lane = tid & 63, wv = tid >> 6;
  if (lane == 0) {
#pragma unroll
    for (int f=0; f<16; ++f) { red[wv][2*f] = s[f]; red[wv][2*f+1] = q[f]; }
  }
  __syncthreads();
  if (tid < 32) {
    float v = red[0][tid] + red[1][tid] + red[2][tid] + red[3][tid];
    part[blockIdx.x*32 + tid] = v;
  }
}

// ---------------- reduce partials + finalize scale/shift ----------------
// grid = C blocks; partial layout part[blk][2C] interleaved (s,q)
__global__ __launch_bounds__(256) void k_reduce_finalize(
    const float* __restrict__ part, int nblk, int C,
    const float* __restrict__ g, const float* __restrict__ b,
    float* __restrict__ prm, float invN)
{
  __shared__ float red[4][2];
  const int c = blockIdx.x;
  const int tid = threadIdx.x;
  float s=0.f, q=0.f;
  for (int i=tid; i<nblk; i+=256) {
    s += part[(size_t)i*2*C + 2*c];
    q += part[(size_t)i*2*C + 2*c + 1];
  }
#pragma unroll
  for (int d=32; d>0; d>>=1) { s += __shfl_down(s,d); q += __shfl_down(q,d); }
  const int lane = tid & 63, wv = tid >> 6;
  if (lane==0) { red[wv][0]=s; red[wv][1]=q; }
  __syncthreads();
  if (tid==0) {
    s = red[0][0]+red[1][0]+red[2][0]+red[3][0];
    q = red[0][1]+red[1][1]+red[2][1]+red[3][1];
    float m = s*invN;
    float v = q*invN - m*m;
    float sc = g[c] / sqrtf(v + EPS);
    prm[2*c]   = sc;
    prm[2*c+1] = fmaf(-m, sc, b[c]);
  }
}

// ---------------- conv1(recompute)+bn1+prelu -> conv2 -> raw out + bn2 partials ----------------
__global__ __launch_bounds__(256) void k_conv2(
    const float* __restrict__ x,
    const float* __restrict__ w1, const float* __restrict__ b1,
    const float* __restrict__ prm1, const float* __restrict__ prelu1,
    const float* __restrict__ w2, const float* __restrict__ b2,
    float* __restrict__ sig, float* __restrict__ part2)
{
  __shared__ float xb[1024];
  __shared__ float h1p[16*136];
  __shared__ float w2s[32*16*12];
  __shared__ float w1s[128];
  __shared__ float p1s[32];
  int tid = threadIdx.x; int b = blockIdx.x;
  *(float4*)&xb[tid*4] = *(const float4*)&x[b*1024 + tid*4];
  for (int i=tid; i<5120; i+=256) { int ff=i/10, k=i-ff*10; w2s[ff*12+k] = w2[i]; }
  if (tid<128) w1s[tid] = w1[tid];
  if (tid<32)  p1s[tid] = prm1[tid];
  float a1 = prelu1[0];
  __syncthreads();
#pragma unroll
  for (int r=0; r<8; ++r) {
    int o = tid + 256*r; int f = o>>7, t = o&127;
    float v = b1[f];
#pragma unroll
    for (int ch=0; ch<8; ++ch) v = fmaf(xb[ch*128+t], w1s[f*8+ch], v);
    v = fmaf(v, p1s[2*f], p1s[2*f+1]);
    v = (v>=0.f) ? v : a1*v;
    h1p[f*136 + t] = v;
  }
  __syncthreads();
  int f2 = tid>>3, wb = (tid&7)*8;
  float acc[8];
  float bb = b2[f2];
#pragma unroll
  for (int j=0;j<8;++j) acc[j]=bb;
  for (int f1=0; f1<16; ++f1) {
    const float* hrow = &h1p[f1*136 + 2*wb];
    float hw[24];
#pragma unroll
    for (int m=0;m<6;++m) *(float4*)&hw[m*4] = *(const float4*)&hrow[m*4];
    const float* wr = &w2s[(f2*16+f1)*12];
    float wk[10];
    *(float4*)&wk[0] = *(const float4*)&wr[0];
    *(float4*)&wk[4] = *(const float4*)&wr[4];
    wk[8]=wr[8]; wk[9]=wr[9];
#pragma unroll
    for (int j=0;j<8;++j)
#pragma unroll
      for (int k=0;k<10;++k) acc[j] = fmaf(hw[2*j+k], wk[k], acc[j]);
  }
  float s=0.f, q=0.f;
#pragma unroll
  for (int j=0;j<8;++j) {
    int w = wb+j;
    if (w < 60) { sig[b*1920 + f2*60 + w] = acc[j]; s += acc[j]; q = fmaf(acc[j],acc[j],q); }
  }
  s += __shfl_down(s,4,8); q += __shfl_down(q,4,8);
  s += __shfl_down(s,2,8); q += __shfl_down(q,2,8);
  s += __shfl_down(s,1,8); q += __shfl_down(q,1,8);
  if ((tid&7)==0) {
    part2[(size_t)b*64 + 2*f2]     = s;
    part2[(size_t)b*64 + 2*f2 + 1] = q;
  }
}

// ---------------- cosine table for 60-pt real-FFT ----------------
__global__ void k_costab(float* __restrict__ ct)
{
  int i = blockIdx.x*256 + threadIdx.x;
  if (i < 3600) {
    int k = i/60, n = i - k*60;
    int m = (k*n) % 60;
    ct[i] = cosf(0.104719755119659775f * (float)m);  // 2*pi/60
  }
}

// ---------------- bn2-apply + prelu (in-place sig) + 60-pt cos transform -> fft ----------------
__global__ __launch_bounds__(256) void k_sigfft(
    float* __restrict__ sig, float* __restrict__ fft,
    const float* __restrict__ prm2, const float* __restrict__ prelu2,
    const float* __restrict__ ctab)
{
  __shared__ float ct[3600];
  __shared__ float rowb[4*60];
  int tid = threadIdx.x;
  for (int i=tid; i<3600; i+=256) ct[i] = ctab[i];
  int r4 = tid>>6, lane = tid&63;
  int row = blockIdx.x*4 + r4;        // (b,c), 131072 rows
  int c = row & 31;
  float a2 = prelu2[0];
  float sc = prm2[2*c], sh = prm2[2*c+1];
  size_t base = (size_t)row*60;
  if (lane < 60) {
    float v = fmaf(sig[base+lane], sc, sh);
    v = (v>=0.f) ? v : a2*v;
    rowb[r4*60+lane] = v;
    sig[base+lane] = v;
  }
  __syncthreads();
  if (lane < 60) {
    float s = 0.f;
    const float* rb = &rowb[r4*60];
#pragma unroll 6
    for (int n=0; n<60; ++n) s = fmaf(rb[n], ct[n*60+lane], s);
    fft[base+lane] = s;
  }
}

// ---------------- bidirectional LSTM; lane=sample, wave=hidden pair ----------------
// grid (64 sample-blocks, 2 dirs, nbranch), 1024 threads (16 waves)
__global__ __launch_bounds__(1024) void k_lstm(
    const float* __restrict__ inA, const float* __restrict__ inB,
    float* __restrict__ outA, float* __restrict__ outB,
    const float* __restrict__ wihf, const float* __restrict__ whhf,
    const float* __restrict__ bihf, const float* __restrict__ bhhf,
    const float* __restrict__ wihr, const float* __restrict__ whhr,
    const float* __restrict__ bihr, const float* __restrict__ bhhr,
    int accmode)
{
  __shared__ float A[64*68];          // [sample][k] : k<32 = x_t, k in [32,64) = h
  const int tid  = threadIdx.x;
  const int lane = tid & 63;
  const int wid  = __builtin_amdgcn_readfirstlane(tid >> 6);  // wave-uniform hidden group
  const int sb   = blockIdx.x * 64;
  const int dir  = blockIdx.y;
  const float* in  = blockIdx.z ? inB : inA;
  float*       out = blockIdx.z ? outB : outA;
  const float* wih = dir ? wihr : wihf;
  const float* whh = dir ? whhr : whhf;
  const float* bih = dir ? bihr : bihf;
  const float* bhh = dir ? bhhr : bhhf;
  const int j0  = wid*2;
  const int col = dir ? 32 : 0;

  float bias[8];
#pragma unroll
  for (int gg=0; gg<4; ++gg) {
    bias[gg]   = bih[j0+32*gg]   + bhh[j0+32*gg];
    bias[4+gg] = bih[j0+32*gg+1] + bhh[j0+32*gg+1];
  }
  // zero h region (each wave zeroes its own 2 columns for all 64 samples)
  *(float2*)&A[lane*68 + 32 + j0] = make_float2(0.f, 0.f);
  // stage X for first step
  {
    const int t0 = dir ? 59 : 0;
    const int e = tid*2;
    float2 xv = *(const float2*)(in + (size_t)t0*131072 + (size_t)sb*32 + e);
    *(float2*)&A[(e>>5)*68 + (e&31)] = xv;
  }
  float c0 = 0.f, c1 = 0.f;
  __syncthreads();

  for (int q=0; q<60; ++q) {
    const int t = dir ? (59-q) : q;
    float2 xnext = make_float2(0.f, 0.f);
    if (q < 59) {
      const int tn = dir ? (58-q) : (q+1);
      xnext = *(const float2*)(in + (size_t)tn*131072 + (size_t)sb*32 + tid*2);
    }
    float acc[8];
#pragma unroll
    for (int r=0;r<8;++r) acc[r] = bias[r];
    const float* Ax = &A[lane*68];
#pragma unroll
    for (int k=0; k<32; k+=4) {
      const float4 av = *(const float4*)(Ax + k);
#pragma unroll
      for (int gg=0; gg<4; ++gg) {
        const float4 w0 = *(const float4*)(wih + (j0+32*gg)*32 + k);
        const float4 w1 = *(const float4*)(wih + (j0+32*gg+1)*32 + k);
        acc[gg]   = fmaf(av.w,w0.w, fmaf(av.z,w0.z, fmaf(av.y,w0.y, fmaf(av.x,w0.x, acc[gg]))));
        acc[4+gg] = fmaf(av.w,w1.w, fmaf(av.z,w1.z, fmaf(av.y,w1.y, fmaf(av.x,w1.x, acc[4+gg]))));
      }
    }
#pragma unroll
    for (int k=0; k<32; k+=4) {
      const float4 av = *(const float4*)(Ax + 32 + k);
#pragma unroll
      for (int gg=0; gg<4; ++gg) {
        const float4 w0 = *(const float4*)(whh + (j0+32*gg)*32 + k);
        const float4 w1 = *(const float4*)(whh + (j0+32*gg+1)*32 + k);
        acc[gg]   = fmaf(av.w,w0.w, fmaf(av.z,w0.z, fmaf(av.y,w0.y, fmaf(av.x,w0.x, acc[gg]))));
        acc[4+gg] = fmaf(av.w,w1.w, fmaf(av.z,w1.z, fmaf(av.y,w1.y, fmaf(av.x,w1.x, acc[4+gg]))));
      }
    }
    // i=acc[0], f=acc[1], g=acc[2], o=acc[3] (and 4..7 for j0+1)
    float c0n = sigf(acc[1])*c0 + sigf(acc[0])*tanhfast(acc[2]);
    float h0n = sigf(acc[3])*tanhfast(c0n);
    c0 = c0n;
    float c1n = sigf(acc[5])*c1 + sigf(acc[4])*tanhfast(acc[6]);
    float h1n = sigf(acc[7])*tanhfast(c1n);
    c1 = c1n;
    __syncthreads();                                  // everyone done reading old A
    *(float2*)&A[lane*68 + 32 + j0] = make_float2(h0n, h1n);
    if (q < 59) {
      const int e = tid*2;
      *(float2*)&A[(e>>5)*68 + (e&31)] = xnext;
    }
    __syncthreads();                                  // new h + next X visible
    // coalesced copy-out of this step's h tile
    {
      const int e = tid*2;
      const int s = e>>5, j = e&31;
      float2 hv = *(const float2*)&A[s*68 + 32 + j];
      float* dst = out + (size_t)t*262144 + (size_t)(sb+s)*64 + col + j;
      if (accmode) { hv.x += dst[0]; hv.y += dst[1]; }
      *(float2*)dst = hv;
    }
  }
}

// ---------------- bnf stats over (4096 rows x 3840 features) ----------------
__global__ __launch_bounds__(256) void k_bnfstats(const float* __restrict__ rb, float* __restrict__ acc)
{
  int col = blockIdx.x*256 + threadIdx.x;            // 0..3839
  size_t r0 = (size_t)blockIdx.y*256;
  const float* p = rb + r0*3840 + col;
  float s=0.f, q=0.f;
  for (int r=0; r<256; ++r) { float v = p[(size_t)r*3840]; s += v; q = fmaf(v,v,q); }
  atomicAdd(&acc[2*col], s); atomicAdd(&acc[2*col+1], q);
}

// ---------------- finalize for atomically-accumulated stats ----------------
__global__ void k_finalize_bn(const float* __restrict__ acc, const float* __restrict__ g,
                              const float* __restrict__ b, float* __restrict__ prm,
                              int C, float invN)
{
  int i = blockIdx.x*blockDim.x + threadIdx.x;
  if (i < C) {
    float m = acc[2*i]*invN;
    float v = acc[2*i+1]*invN - m*m;
    float sc = g[i] / sqrtf(v + EPS);
    prm[2*i]   = sc;
    prm[2*i+1] = fmaf(-m, sc, b[i]);
  }
}

// ---------------- bn1d-apply + correlation + final 5-tap conv ----------------
__global__ __launch_bounds__(64) void k_corr(
    const float* __restrict__ ra, const float* __restrict__ rb,
    const float* __restrict__ pfa, const float* __restrict__ pfb,
    const float* __restrict__ cw, const float* __restrict__ cb,
    float* __restrict__ dout)
{
  __shared__ float sxt[12], sxx[12], stt[12], cv[12];
  int lane = threadIdx.x; int r = blockIdx.x;
  if (lane < 12) { sxt[lane]=0.f; sxx[lane]=0.f; stt[lane]=0.f; }
  __syncthreads();
  const float* pa = ra + (size_t)r*3840;
  const float* pb = rb + (size_t)r*3840;
  float xt0=0,xx0=0,tt0=0, xt1=0,xx1=0,tt1=0, xt2=0,xx2=0,tt2=0;
  for (int i=0; i<60; i+=3) {
    { int fe = lane + 64*i;
      float a = fmaf(pa[fe], pfa[2*fe], pfa[2*fe+1]);
      float b = fmaf(pb[fe], pfb[2*fe], pfb[2*fe+1]);
      xt0 = fmaf(a,b,xt0); xx0 = fmaf(a,a,xx0); tt0 = fmaf(b,b,tt0); }
    { int fe = lane + 64*(i+1);
      float a = fmaf(pa[fe], pfa[2*fe], pfa[2*fe+1]);
      float b = fmaf(pb[fe], pfb[2*fe], pfb[2*fe+1]);
      xt1 = fmaf(a,b,xt1); xx1 = fmaf(a,a,xx1); tt1 = fmaf(b,b,tt1); }
    { int fe = lane + 64*(i+2);
      float a = fmaf(pa[fe], pfa[2*fe], pfa[2*fe+1]);
      float b = fmaf(pb[fe], pfb[2*fe], pfb[2*fe+1]);
      xt2 = fmaf(a,b,xt2); xx2 = fmaf(a,a,xx2); tt2 = fmaf(b,b,tt2); }
  }
  int c0 = lane % 12;
  int c1 = (c0+4) % 12;
  int c2 = (c0+8) % 12;
  atomicAdd(&sxt[c0], xt0); atomicAdd(&sxx[c0], xx0); atomicAdd(&stt[c0], tt0);
  atomicAdd(&sxt[c1], xt1); atomicAdd(&sxx[c1], xx1); atomicAdd(&stt[c1], tt1);
  atomicAdd(&sxt[c2], xt2); atomicAdd(&sxx[c2], xx2); atomicAdd(&stt[c2], tt2);
  __syncthreads();
  if (lane < 12) {
    float corr = sxt[lane] / sqrtf(stt[lane]) / sqrtf(sxx[lane]);
    cv[lane] = corr;
    dout[49152 + r*12 + lane] = corr;
  }
  __syncthreads();
  if (lane < 12) {
    float o = cb[0];
#pragma unroll
    for (int k=0; k<5; ++k) { int j = lane + k - 2; if (j>=0 && j<12) o = fmaf(cv[j], cw[k], o); }
    dout[r*12 + lane] = o;
  }
}

// ---------------- host ----------------
extern "C" void kernel_launch(void* const* d_in, const int* in_sizes, int n_in,
                              void* d_out, int out_size, void* d_ws, size_t ws_size,
                              hipStream_t stream)
{
  const float* x    = (const float*)d_in[0];
  const float* tpl  = (const float*)d_in[1];
  const float* w1   = (const float*)d_in[2];
  const float* b1   = (const float*)d_in[3];
  const float* g1   = (const float*)d_in[4];
  const float* bb1  = (const float*)d_in[5];
  const float* p1   = (const float*)d_in[6];
  const float* w2   = (const float*)d_in[7];
  const float* b2   = (const float*)d_in[8];
  const float* g2   = (const float*)d_in[9];
  const float* bb2  = (const float*)d_in[10];
  const float* p2   = (const float*)d_in[11];
  const float* wihf = (const float*)d_in[12];
  const float* whhf = (const float*)d_in[13];
  const float* bihf = (const float*)d_in[14];
  const float* bhhf = (const float*)d_in[15];
  const float* wihr = (const float*)d_in[16];
  const float* whhr = (const float*)d_in[17];
  const float* bihr = (const float*)d_in[18];
  const float* bhhr = (const float*)d_in[19];
  const float* gf   = (const float*)d_in[20];
  const float* bf   = (const float*)d_in[21];
  const float* cw   = (const float*)d_in[22];
  const float* cb   = (const float*)d_in[23];
  float* W   = (float*)d_ws;
  float* out = (float*)d_out;

  // small scratch (float offsets)
  constexpr size_t PRM1A=64, PRM1B=96, PRM2A=256, PRM2B=320;
  constexpr size_t ACCFA=512, ACCFB=8192, PRMFA=15872, PRMFB=23552, CTAB=31232;
  constexpr size_t P1P=35072;               // 256*32   = 8192  -> ends 43264
  constexpr size_t P2P=43264;               // 4096*64  = 262144 -> ends 305408
  constexpr size_t SIGSZ = 7864320, RSZ = 15728640;
  constexpr size_t BIG0 = 307200;
  // fast layout: sigA | fftA | sigB | fftB | rbufA | rbufB
  constexpr size_t F_SIGA=BIG0, F_FFTA=F_SIGA+SIGSZ, F_SIGB=F_FFTA+SIGSZ, F_FFTB=F_SIGB+SIGSZ;
  constexpr size_t F_RBUFA=F_FFTB+SIGSZ, F_RBUFB=F_RBUFA+RSZ;
  constexpr size_t F_TOTAL=(F_RBUFB+RSZ)*sizeof(float);
  // sequential layout: sig | fft | rbufA | rbufB
  constexpr size_t S_SIG=BIG0, S_FFT=S_SIG+SIGSZ, S_RBUFA=S_FFT+SIGSZ, S_RBUFB=S_RBUFA+RSZ;

  const bool fast = ws_size >= F_TOTAL;

  hipMemsetAsync(W, 0, 65536, stream);               // zero bnf stat accumulators
  k_costab<<<15,256,0,stream>>>(W+CTAB);

  for (int br=0; br<2; ++br) {
    const float* xin  = br ? tpl : x;
    float* prm1 = W + (br ? PRM1B : PRM1A);
    float* prm2 = W + (br ? PRM2B : PRM2A);
    float* sig  = W + (fast ? (br ? F_SIGB : F_SIGA) : S_SIG);
    float* fft  = W + (fast ? (br ? F_FFTB : F_FFTA) : S_FFT);
    float* rbuf = W + (fast ? (br ? F_RBUFB : F_RBUFA) : (br ? S_RBUFB : S_RBUFA));
    k_conv1_stats<<<256,256,0,stream>>>(xin, w1, b1, W+P1P);
    k_reduce_finalize<<<16,256,0,stream>>>(W+P1P, 256, 16, g1, bb1, prm1, 1.f/524288.f);
    k_conv2<<<4096,256,0,stream>>>(xin, w1, b1, prm1, p1, w2, b2, sig, W+P2P);
    k_reduce_finalize<<<32,256,0,stream>>>(W+P2P, 4096, 32, g2, bb2, prm2, 1.f/245760.f);
    k_sigfft<<<32768,256,0,stream>>>(sig, fft, prm2, p2, W+CTAB);
    if (!fast) {
      k_lstm<<<dim3(64,2,1),1024,0,stream>>>(sig, sig, rbuf, rbuf,
                                             wihf,whhf,bihf,bhhf, wihr,whhr,bihr,bhhr, 0);
      k_lstm<<<dim3(64,2,1),1024,0,stream>>>(fft, fft, rbuf, rbuf,
                                             wihf,whhf,bihf,bhhf, wihr,whhr,bihr,bhhr, 1);
    }
  }

  float* rbufA = W + (fast ? F_RBUFA : S_RBUFA);
  float* rbufB = W + (fast ? F_RBUFB : S_RBUFB);

  if (fast) {
    k_lstm<<<dim3(64,2,2),1024,0,stream>>>(W+F_SIGA, W+F_SIGB, rbufA, rbufB,
                                           wihf,whhf,bihf,bhhf, wihr,whhr,bihr,bhhr, 0);
    k_lstm<<<dim3(64,2,2),1024,0,stream>>>(W+F_FFTA, W+F_FFTB, rbufA, rbufB,
                                           wihf,whhf,bihf,bhhf, wihr,whhr,bihr,bhhr, 1);
  }

  k_bnfstats<<<dim3(15,16),256,0,stream>>>(rbufA, W+ACCFA);
  k_bnfstats<<<dim3(15,16),256,0,stream>>>(rbufB, W+ACCFB);
  k_finalize_bn<<<15,256,0,stream>>>(W+ACCFA, gf, bf, W+PRMFA, 3840, 1.f/4096.f);
  k_finalize_bn<<<15,256,0,stream>>>(W+ACCFB, gf, bf, W+PRMFB, 3840, 1.f/4096.f);

  k_corr<<<4096,64,0,stream>>>(rbufA, rbufB, W+PRMFA, W+PRMFB, cw, cb, out);
}

// Round 4
// 1164.880 us; speedup vs baseline: 5.7816x; 1.6513x over previous
//
#include <hip/hip_runtime.h>
#include <math.h>

#define EPS 1e-5f

__device__ __forceinline__ float sigf(float x){ return 1.0f/(1.0f + __expf(-x)); }
__device__ __forceinline__ float tanhfast(float x){ return 2.0f/(1.0f + __expf(-2.0f*x)) - 1.0f; }
__device__ __forceinline__ float dot4(float4 a, float4 b, float c){
  return fmaf(a.w,b.w, fmaf(a.z,b.z, fmaf(a.y,b.y, fmaf(a.x,b.x, c))));
}

// ---------------- conv1 + bn1 partial stats: 256 blocks, register+LDS reduce ----------------
__global__ __launch_bounds__(256) void k_conv1_stats(
    const float* __restrict__ x, const float* __restrict__ w1,
    const float* __restrict__ b1, float* __restrict__ part)
{
  __shared__ float red[4][32];
  float s[16], q[16];
#pragma unroll
  for (int f=0; f<16; ++f) { s[f]=0.f; q[f]=0.f; }
  float w1r[128];
#pragma unroll
  for (int i=0; i<128; ++i) w1r[i] = w1[i];
  float b1r[16];
#pragma unroll
  for (int f=0; f<16; ++f) b1r[f] = b1[f];
  const int tid = threadIdx.x;
  for (int iter=0; iter<8; ++iter) {
    int n = blockIdx.x*2048 + iter*256 + tid;      // (b,t), 524288 total
    int b = n >> 7, t = n & 127;
    const float* xb = x + b*1024 + t;
    float xv[8];
#pragma unroll
    for (int ch=0; ch<8; ++ch) xv[ch] = xb[ch*128];
#pragma unroll
    for (int f=0; f<16; ++f) {
      float v = b1r[f];
#pragma unroll
      for (int ch=0; ch<8; ++ch) v = fmaf(xv[ch], w1r[f*8+ch], v);
      s[f] += v; q[f] = fmaf(v,v,q[f]);
    }
  }
#pragma unroll
  for (int f=0; f<16; ++f) {
#pragma unroll
    for (int d=32; d>0; d>>=1) { s[f] += __shfl_down(s[f],d); q[f] += __shfl_down(q[f],d); }
  }
  const int lane = tid & 63, wv = tid >> 6;
  if (lane == 0) {
#pragma unroll
    for (int f=0; f<16; ++f) { red[wv][2*f] = s[f]; red[wv][2*f+1] = q[f]; }
  }
  __syncthreads();
  if (tid < 32) {
    float v = red[0][tid] + red[1][tid] + red[2][tid] + red[3][tid];
    part[blockIdx.x*32 + tid] = v;
  }
}

// ---------------- reduce partials + finalize scale/shift ----------------
__global__ __launch_bounds__(256) void k_reduce_finalize(
    const float* __restrict__ part, int nblk, int C,
    const float* __restrict__ g, const float* __restrict__ b,
    float* __restrict__ prm, float invN)
{
  __shared__ float red[4][2];
  const int c = blockIdx.x;
  const int tid = threadIdx.x;
  float s=0.f, q=0.f;
  for (int i=tid; i<nblk; i+=256) {
    s += part[(size_t)i*2*C + 2*c];
    q += part[(size_t)i*2*C + 2*c + 1];
  }
#pragma unroll
  for (int d=32; d>0; d>>=1) { s += __shfl_down(s,d); q += __shfl_down(q,d); }
  const int lane = tid & 63, wv = tid >> 6;
  if (lane==0) { red[wv][0]=s; red[wv][1]=q; }
  __syncthreads();
  if (tid==0) {
    s = red[0][0]+red[1][0]+red[2][0]+red[3][0];
    q = red[0][1]+red[1][1]+red[2][1]+red[3][1];
    float m = s*invN;
    float v = q*invN - m*m;
    float sc = g[c] / sqrtf(v + EPS);
    prm[2*c]   = sc;
    prm[2*c+1] = fmaf(-m, sc, b[c]);
  }
}

// ---------------- conv1(recompute)+bn1+prelu -> conv2 -> raw out + bn2 partials ----------------
__global__ __launch_bounds__(256) void k_conv2(
    const float* __restrict__ x,
    const float* __restrict__ w1, const float* __restrict__ b1,
    const float* __restrict__ prm1, const float* __restrict__ prelu1,
    const float* __restrict__ w2, const float* __restrict__ b2,
    float* __restrict__ sig, float* __restrict__ part2)
{
  __shared__ float xb[1024];
  __shared__ float h1p[16*136];
  __shared__ float w2s[32*16*12];
  __shared__ float w1s[128];
  __shared__ float p1s[32];
  int tid = threadIdx.x; int b = blockIdx.x;
  *(float4*)&xb[tid*4] = *(const float4*)&x[b*1024 + tid*4];
  for (int i=tid; i<5120; i+=256) { int ff=i/10, k=i-ff*10; w2s[ff*12+k] = w2[i]; }
  if (tid<128) w1s[tid] = w1[tid];
  if (tid<32)  p1s[tid] = prm1[tid];
  float a1 = prelu1[0];
  __syncthreads();
#pragma unroll
  for (int r=0; r<8; ++r) {
    int o = tid + 256*r; int f = o>>7, t = o&127;
    float v = b1[f];
#pragma unroll
    for (int ch=0; ch<8; ++ch) v = fmaf(xb[ch*128+t], w1s[f*8+ch], v);
    v = fmaf(v, p1s[2*f], p1s[2*f+1]);
    v = (v>=0.f) ? v : a1*v;
    h1p[f*136 + t] = v;
  }
  __syncthreads();
  int f2 = tid>>3, wb = (tid&7)*8;
  float acc[8];
  float bb = b2[f2];
#pragma unroll
  for (int j=0;j<8;++j) acc[j]=bb;
  for (int f1=0; f1<16; ++f1) {
    const float* hrow = &h1p[f1*136 + 2*wb];
    float hw[24];
#pragma unroll
    for (int m=0;m<6;++m) *(float4*)&hw[m*4] = *(const float4*)&hrow[m*4];
    const float* wr = &w2s[(f2*16+f1)*12];
    float wk[10];
    *(float4*)&wk[0] = *(const float4*)&wr[0];
    *(float4*)&wk[4] = *(const float4*)&wr[4];
    wk[8]=wr[8]; wk[9]=wr[9];
#pragma unroll
    for (int j=0;j<8;++j)
#pragma unroll
      for (int k=0;k<10;++k) acc[j] = fmaf(hw[2*j+k], wk[k], acc[j]);
  }
  float s=0.f, q=0.f;
#pragma unroll
  for (int j=0;j<8;++j) {
    int w = wb+j;
    if (w < 60) { sig[b*1920 + f2*60 + w] = acc[j]; s += acc[j]; q = fmaf(acc[j],acc[j],q); }
  }
  s += __shfl_down(s,4,8); q += __shfl_down(q,4,8);
  s += __shfl_down(s,2,8); q += __shfl_down(q,2,8);
  s += __shfl_down(s,1,8); q += __shfl_down(q,1,8);
  if ((tid&7)==0) {
    part2[(size_t)b*64 + 2*f2]     = s;
    part2[(size_t)b*64 + 2*f2 + 1] = q;
  }
}

// ---------------- cosine table for 60-pt real-FFT ----------------
__global__ void k_costab(float* __restrict__ ct)
{
  int i = blockIdx.x*256 + threadIdx.x;
  if (i < 3600) {
    int k = i/60, n = i - k*60;
    int m = (k*n) % 60;
    ct[i] = cosf(0.104719755119659775f * (float)m);  // 2*pi/60
  }
}

// ---------------- bn2-apply + prelu (in-place sig) + 60-pt cos transform -> fft ----------------
__global__ __launch_bounds__(256) void k_sigfft(
    float* __restrict__ sig, float* __restrict__ fft,
    const float* __restrict__ prm2, const float* __restrict__ prelu2,
    const float* __restrict__ ctab)
{
  __shared__ float ct[3600];
  __shared__ float rowb[4*60];
  int tid = threadIdx.x;
  for (int i=tid; i<3600; i+=256) ct[i] = ctab[i];
  int r4 = tid>>6, lane = tid&63;
  int row = blockIdx.x*4 + r4;        // (b,c), 131072 rows
  int c = row & 31;
  float a2 = prelu2[0];
  float sc = prm2[2*c], sh = prm2[2*c+1];
  size_t base = (size_t)row*60;
  if (lane < 60) {
    float v = fmaf(sig[base+lane], sc, sh);
    v = (v>=0.f) ? v : a2*v;
    rowb[r4*60+lane] = v;
    sig[base+lane] = v;
  }
  __syncthreads();
  if (lane < 60) {
    float s = 0.f;
    const float* rb = &rowb[r4*60];
#pragma unroll 6
    for (int n=0; n<60; ++n) s = fmaf(rb[n], ct[n*60+lane], s);
    fft[base+lane] = s;
  }
}

// ---------------- fused bidirectional LSTM over sig+fft streams ----------------
// wave = one (sample, dir, branch); lane l: unit u=l&31, half=l>>5
// half0 owns gate rows {u (i), 64+u (g)}, half1 owns {32+u (f), 96+u (o)}
// weights register-resident (128 VGPR/lane); x,h broadcast from private LDS slice
__global__ __launch_bounds__(256,2) void k_lstm_fused(
    const float* __restrict__ sigA, const float* __restrict__ sigB,
    const float* __restrict__ fftA, const float* __restrict__ fftB,
    float* __restrict__ routA, float* __restrict__ routB,
    const float* __restrict__ wihf, const float* __restrict__ whhf,
    const float* __restrict__ bihf, const float* __restrict__ bhhf,
    const float* __restrict__ wihr, const float* __restrict__ whhr,
    const float* __restrict__ bihr, const float* __restrict__ bhhr)
{
  __shared__ float L[4][3904];     // per wave: XS[60][32] | XF[60][32] | H1[32] | H2[32]
  const int tid  = threadIdx.x;
  const int lane = tid & 63;
  const int w    = tid >> 6;
  const int u    = lane & 31;
  const int half = lane >> 5;
  const int s    = blockIdx.x*4 + w;
  const int dir  = blockIdx.y;
  const float* in1 = blockIdx.z ? sigB : sigA;
  const float* in2 = blockIdx.z ? fftB : fftA;
  float*       out = blockIdx.z ? routB : routA;
  const float* wih = dir ? wihr : wihf;
  const float* whh = dir ? whhr : whhf;
  const float* bih = dir ? bihr : bihf;
  const float* bhh = dir ? bhhr : bhhf;

  float* XS = &L[w][0];
  float* XF = &L[w][1920];
  float* H1 = &L[w][3840];
  float* H2 = &L[w][3872];

  // stage both x streams (coalesced float4), zero h
  for (int i = lane; i < 480; i += 64) {
    int t = i >> 3, q4 = (i & 7) * 4;
    *(float4*)&XS[t*32 + q4] = *(const float4*)&in1[(size_t)t*131072 + (size_t)s*32 + q4];
    *(float4*)&XF[t*32 + q4] = *(const float4*)&in2[(size_t)t*131072 + (size_t)s*32 + q4];
  }
  if (half == 0) { H1[u] = 0.f; H2[u] = 0.f; }

  // register-resident weights: rows rA, rB of wih and whh
  const int rA = half*32 + u;
  const int rB = 64 + half*32 + u;
  float4 wxA[8], wxB[8], whA[8], whB[8];
#pragma unroll
  for (int m=0; m<8; ++m) {
    wxA[m] = *(const float4*)&wih[rA*32 + m*4];
    wxB[m] = *(const float4*)&wih[rB*32 + m*4];
    whA[m] = *(const float4*)&whh[rA*32 + m*4];
    whB[m] = *(const float4*)&whh[rB*32 + m*4];
  }
  const float bA = bih[rA] + bhh[rA];
  const float bB = bih[rB] + bhh[rB];

  float c1 = 0.f, c2 = 0.f;
  const size_t obase = (size_t)s*64 + dir*32 + u;

  for (int q = 0; q < 60; ++q) {
    const int tt = dir ? (59 - q) : q;
    float a1A = bA, a1B = bB, a2A = bA, a2B = bB;
    const float* xs = &XS[tt*32];
    const float* xf = &XF[tt*32];
#pragma unroll
    for (int m=0; m<8; ++m) {
      float4 v1 = *(const float4*)&xs[m*4];
      float4 v2 = *(const float4*)&xf[m*4];
      a1A = dot4(v1, wxA[m], a1A); a1B = dot4(v1, wxB[m], a1B);
      a2A = dot4(v2, wxA[m], a2A); a2B = dot4(v2, wxB[m], a2B);
    }
#pragma unroll
    for (int m=0; m<8; ++m) {
      float4 v1 = *(const float4*)&H1[m*4];
      float4 v2 = *(const float4*)&H2[m*4];
      a1A = dot4(v1, whA[m], a1A); a1B = dot4(v1, whB[m], a1B);
      a2A = dot4(v2, whA[m], a2A); a2B = dot4(v2, whB[m], a2B);
    }
    // exchange across halves: half0 holds (i,g), half1 holds (f,o)
    float x1A = __shfl_xor(a1A, 32), x1B = __shfl_xor(a1B, 32);
    float x2A = __shfl_xor(a2A, 32), x2B = __shfl_xor(a2B, 32);
    float gi1 = half ? x1A : a1A, gf1 = half ? a1A : x1A;
    float gg1 = half ? x1B : a1B, go1 = half ? a1B : x1B;
    float gi2 = half ? x2A : a2A, gf2 = half ? a2A : x2A;
    float gg2 = half ? x2B : a2B, go2 = half ? a2B : x2B;
    c1 = sigf(gf1)*c1 + sigf(gi1)*tanhfast(gg1);
    float h1 = sigf(go1)*tanhfast(c1);
    c2 = sigf(gf2)*c2 + sigf(gi2)*tanhfast(gg2);
    float h2 = sigf(go2)*tanhfast(c2);
    if (half == 0) {
      H1[u] = h1; H2[u] = h2;
      out[(size_t)tt*262144 + obase] = h1 + h2;
    }
  }
}

// ---------------- bnf stats over (4096 rows x 3840 features) ----------------
__global__ __launch_bounds__(256) void k_bnfstats(const float* __restrict__ rb, float* __restrict__ acc)
{
  int col = blockIdx.x*256 + threadIdx.x;            // 0..3839
  size_t r0 = (size_t)blockIdx.y*256;
  const float* p = rb + r0*3840 + col;
  float s=0.f, q=0.f;
  for (int r=0; r<256; ++r) { float v = p[(size_t)r*3840]; s += v; q = fmaf(v,v,q); }
  atomicAdd(&acc[2*col], s); atomicAdd(&acc[2*col+1], q);
}

// ---------------- finalize for atomically-accumulated stats ----------------
__global__ void k_finalize_bn(const float* __restrict__ acc, const float* __restrict__ g,
                              const float* __restrict__ b, float* __restrict__ prm,
                              int C, float invN)
{
  int i = blockIdx.x*blockDim.x + threadIdx.x;
  if (i < C) {
    float m = acc[2*i]*invN;
    float v = acc[2*i+1]*invN - m*m;
    float sc = g[i] / sqrtf(v + EPS);
    prm[2*i]   = sc;
    prm[2*i+1] = fmaf(-m, sc, b[i]);
  }
}

// ---------------- bn1d-apply + correlation + final 5-tap conv ----------------
__global__ __launch_bounds__(64) void k_corr(
    const float* __restrict__ ra, const float* __restrict__ rb,
    const float* __restrict__ pfa, const float* __restrict__ pfb,
    const float* __restrict__ cw, const float* __restrict__ cb,
    float* __restrict__ dout)
{
  __shared__ float sxt[12], sxx[12], stt[12], cv[12];
  int lane = threadIdx.x; int r = blockIdx.x;
  if (lane < 12) { sxt[lane]=0.f; sxx[lane]=0.f; stt[lane]=0.f; }
  __syncthreads();
  const float* pa = ra + (size_t)r*3840;
  const float* pb = rb + (size_t)r*3840;
  float xt0=0,xx0=0,tt0=0, xt1=0,xx1=0,tt1=0, xt2=0,xx2=0,tt2=0;
  for (int i=0; i<60; i+=3) {
    { int fe = lane + 64*i;
      float a = fmaf(pa[fe], pfa[2*fe], pfa[2*fe+1]);
      float b = fmaf(pb[fe], pfb[2*fe], pfb[2*fe+1]);
      xt0 = fmaf(a,b,xt0); xx0 = fmaf(a,a,xx0); tt0 = fmaf(b,b,tt0); }
    { int fe = lane + 64*(i+1);
      float a = fmaf(pa[fe], pfa[2*fe], pfa[2*fe+1]);
      float b = fmaf(pb[fe], pfb[2*fe], pfb[2*fe+1]);
      xt1 = fmaf(a,b,xt1); xx1 = fmaf(a,a,xx1); tt1 = fmaf(b,b,tt1); }
    { int fe = lane + 64*(i+2);
      float a = fmaf(pa[fe], pfa[2*fe], pfa[2*fe+1]);
      float b = fmaf(pb[fe], pfb[2*fe], pfb[2*fe+1]);
      xt2 = fmaf(a,b,xt2); xx2 = fmaf(a,a,xx2); tt2 = fmaf(b,b,tt2); }
  }
  int c0 = lane % 12;
  int c1 = (c0+4) % 12;
  int c2 = (c0+8) % 12;
  atomicAdd(&sxt[c0], xt0); atomicAdd(&sxx[c0], xx0); atomicAdd(&stt[c0], tt0);
  atomicAdd(&sxt[c1], xt1); atomicAdd(&sxx[c1], xx1); atomicAdd(&stt[c1], tt1);
  atomicAdd(&sxt[c2], xt2); atomicAdd(&sxx[c2], xx2); atomicAdd(&stt[c2], tt2);
  __syncthreads();
  if (lane < 12) {
    float corr = sxt[lane] / sqrtf(stt[lane]) / sqrtf(sxx[lane]);
    cv[lane] = corr;
    dout[49152 + r*12 + lane] = corr;
  }
  __syncthreads();
  if (lane < 12) {
    float o = cb[0];
#pragma unroll
    for (int k=0; k<5; ++k) { int j = lane + k - 2; if (j>=0 && j<12) o = fmaf(cv[j], cw[k], o); }
    dout[r*12 + lane] = o;
  }
}

// ---------------- host ----------------
extern "C" void kernel_launch(void* const* d_in, const int* in_sizes, int n_in,
                              void* d_out, int out_size, void* d_ws, size_t ws_size,
                              hipStream_t stream)
{
  const float* x    = (const float*)d_in[0];
  const float* tpl  = (const float*)d_in[1];
  const float* w1   = (const float*)d_in[2];
  const float* b1   = (const float*)d_in[3];
  const float* g1   = (const float*)d_in[4];
  const float* bb1  = (const float*)d_in[5];
  const float* p1   = (const float*)d_in[6];
  const float* w2   = (const float*)d_in[7];
  const float* b2   = (const float*)d_in[8];
  const float* g2   = (const float*)d_in[9];
  const float* bb2  = (const float*)d_in[10];
  const float* p2   = (const float*)d_in[11];
  const float* wihf = (const float*)d_in[12];
  const float* whhf = (const float*)d_in[13];
  const float* bihf = (const float*)d_in[14];
  const float* bhhf = (const float*)d_in[15];
  const float* wihr = (const float*)d_in[16];
  const float* whhr = (const float*)d_in[17];
  const float* bihr = (const float*)d_in[18];
  const float* bhhr = (const float*)d_in[19];
  const float* gf   = (const float*)d_in[20];
  const float* bf   = (const float*)d_in[21];
  const float* cw   = (const float*)d_in[22];
  const float* cb   = (const float*)d_in[23];
  float* W   = (float*)d_ws;
  float* out = (float*)d_out;

  // small scratch (float offsets)
  constexpr size_t PRM1A=64, PRM1B=96, PRM2A=256, PRM2B=320;
  constexpr size_t ACCFA=512, ACCFB=8192, PRMFA=15872, PRMFB=23552, CTAB=31232;
  constexpr size_t P1P=35072;               // 256*32
  constexpr size_t P2P=43264;               // 4096*64
  constexpr size_t SIGSZ = 7864320, RSZ = 15728640;
  constexpr size_t BIG0 = 307200;
  // fast layout: sigA | fftA | sigB | fftB | rbufA | rbufB
  constexpr size_t F_SIGA=BIG0, F_FFTA=F_SIGA+SIGSZ, F_SIGB=F_FFTA+SIGSZ, F_FFTB=F_SIGB+SIGSZ;
  constexpr size_t F_RBUFA=F_FFTB+SIGSZ, F_RBUFB=F_RBUFA+RSZ;
  constexpr size_t F_TOTAL=(F_RBUFB+RSZ)*sizeof(float);
  // sequential layout: sig | fft | rbufA | rbufB
  constexpr size_t S_SIG=BIG0, S_FFT=S_SIG+SIGSZ, S_RBUFA=S_FFT+SIGSZ, S_RBUFB=S_RBUFA+RSZ;

  const bool fast = ws_size >= F_TOTAL;

  hipMemsetAsync(W, 0, 65536, stream);               // zero bnf stat accumulators
  k_costab<<<15,256,0,stream>>>(W+CTAB);

  for (int br=0; br<2; ++br) {
    const float* xin  = br ? tpl : x;
    float* prm1 = W + (br ? PRM1B : PRM1A);
    float* prm2 = W + (br ? PRM2B : PRM2A);
    float* sig  = W + (fast ? (br ? F_SIGB : F_SIGA) : S_SIG);
    float* fft  = W + (fast ? (br ? F_FFTB : F_FFTA) : S_FFT);
    float* rbuf = W + (fast ? (br ? F_RBUFB : F_RBUFA) : (br ? S_RBUFB : S_RBUFA));
    k_conv1_stats<<<256,256,0,stream>>>(xin, w1, b1, W+P1P);
    k_reduce_finalize<<<16,256,0,stream>>>(W+P1P, 256, 16, g1, bb1, prm1, 1.f/524288.f);
    k_conv2<<<4096,256,0,stream>>>(xin, w1, b1, prm1, p1, w2, b2, sig, W+P2P);
    k_reduce_finalize<<<32,256,0,stream>>>(W+P2P, 4096, 32, g2, bb2, prm2, 1.f/245760.f);
    k_sigfft<<<32768,256,0,stream>>>(sig, fft, prm2, p2, W+CTAB);
    if (!fast) {
      // per-branch fused LSTM (z-grid 1, A-pointers only)
      k_lstm_fused<<<dim3(1024,2,1),256,0,stream>>>(sig, sig, fft, fft, rbuf, rbuf,
                                                    wihf,whhf,bihf,bhhf, wihr,whhr,bihr,bhhr);
    }
  }

  float* rbufA = W + (fast ? F_RBUFA : S_RBUFA);
  float* rbufB = W + (fast ? F_RBUFB : S_RBUFB);

  if (fast) {
    k_lstm_fused<<<dim3(1024,2,2),256,0,stream>>>(W+F_SIGA, W+F_SIGB, W+F_FFTA, W+F_FFTB,
                                                  rbufA, rbufB,
                                                  wihf,whhf,bihf,bhhf, wihr,whhr,bihr,bhhr);
  }

  k_bnfstats<<<dim3(15,16),256,0,stream>>>(rbufA, W+ACCFA);
  k_bnfstats<<<dim3(15,16),256,0,stream>>>(rbufB, W+ACCFB);
  k_finalize_bn<<<15,256,0,stream>>>(W+ACCFA, gf, bf, W+PRMFA, 3840, 1.f/4096.f);
  k_finalize_bn<<<15,256,0,stream>>>(W+ACCFB, gf, bf, W+PRMFB, 3840, 1.f/4096.f);

  k_corr<<<4096,64,0,stream>>>(rbufA, rbufB, W+PRMFA, W+PRMFB, cw, cb, out);
}

// Round 5
// 1049.880 us; speedup vs baseline: 6.4149x; 1.1095x over previous
//
#include <hip/hip_runtime.h>
#include <math.h>

#define EPS 1e-5f

__device__ __forceinline__ float fast_rcp(float x){ return __builtin_amdgcn_rcpf(x); }
__device__ __forceinline__ float sigf(float x){ return fast_rcp(1.0f + __expf(-x)); }
__device__ __forceinline__ float tanhfast(float x){ return fmaf(2.0f, fast_rcp(1.0f + __expf(-2.0f*x)), -1.0f); }
__device__ __forceinline__ float dot4(float4 a, float4 b, float c){
  return fmaf(a.w,b.w, fmaf(a.z,b.z, fmaf(a.y,b.y, fmaf(a.x,b.x, c))));
}
#define PIN4(v) asm volatile("" : "+v"((v).x), "+v"((v).y), "+v"((v).z), "+v"((v).w))

// ---------------- conv1 + bn1 partial stats: 256 blocks, register+LDS reduce ----------------
__global__ __launch_bounds__(256) void k_conv1_stats(
    const float* __restrict__ x, const float* __restrict__ w1,
    const float* __restrict__ b1, float* __restrict__ part)
{
  __shared__ float red[4][32];
  float s[16], q[16];
#pragma unroll
  for (int f=0; f<16; ++f) { s[f]=0.f; q[f]=0.f; }
  float w1r[128];
#pragma unroll
  for (int i=0; i<128; ++i) w1r[i] = w1[i];
  float b1r[16];
#pragma unroll
  for (int f=0; f<16; ++f) b1r[f] = b1[f];
  const int tid = threadIdx.x;
  for (int iter=0; iter<8; ++iter) {
    int n = blockIdx.x*2048 + iter*256 + tid;      // (b,t), 524288 total
    int b = n >> 7, t = n & 127;
    const float* xb = x + b*1024 + t;
    float xv[8];
#pragma unroll
    for (int ch=0; ch<8; ++ch) xv[ch] = xb[ch*128];
#pragma unroll
    for (int f=0; f<16; ++f) {
      float v = b1r[f];
#pragma unroll
      for (int ch=0; ch<8; ++ch) v = fmaf(xv[ch], w1r[f*8+ch], v);
      s[f] += v; q[f] = fmaf(v,v,q[f]);
    }
  }
#pragma unroll
  for (int f=0; f<16; ++f) {
#pragma unroll
    for (int d=32; d>0; d>>=1) { s[f] += __shfl_down(s[f],d); q[f] += __shfl_down(q[f],d); }
  }
  const int lane = tid & 63, wv = tid >> 6;
  if (lane == 0) {
#pragma unroll
    for (int f=0; f<16; ++f) { red[wv][2*f] = s[f]; red[wv][2*f+1] = q[f]; }
  }
  __syncthreads();
  if (tid < 32) {
    float v = red[0][tid] + red[1][tid] + red[2][tid] + red[3][tid];
    part[blockIdx.x*32 + tid] = v;
  }
}

// ---------------- reduce partials + finalize scale/shift ----------------
__global__ __launch_bounds__(256) void k_reduce_finalize(
    const float* __restrict__ part, int nblk, int C,
    const float* __restrict__ g, const float* __restrict__ b,
    float* __restrict__ prm, float invN)
{
  __shared__ float red[4][2];
  const int c = blockIdx.x;
  const int tid = threadIdx.x;
  float s=0.f, q=0.f;
  for (int i=tid; i<nblk; i+=256) {
    s += part[(size_t)i*2*C + 2*c];
    q += part[(size_t)i*2*C + 2*c + 1];
  }
#pragma unroll
  for (int d=32; d>0; d>>=1) { s += __shfl_down(s,d); q += __shfl_down(q,d); }
  const int lane = tid & 63, wv = tid >> 6;
  if (lane==0) { red[wv][0]=s; red[wv][1]=q; }
  __syncthreads();
  if (tid==0) {
    s = red[0][0]+red[1][0]+red[2][0]+red[3][0];
    q = red[0][1]+red[1][1]+red[2][1]+red[3][1];
    float m = s*invN;
    float v = q*invN - m*m;
    float sc = g[c] / sqrtf(v + EPS);
    prm[2*c]   = sc;
    prm[2*c+1] = fmaf(-m, sc, b[c]);
  }
}

// ---------------- conv1(recompute)+bn1+prelu -> conv2 -> raw out + bn2 partials ----------------
__global__ __launch_bounds__(256) void k_conv2(
    const float* __restrict__ x,
    const float* __restrict__ w1, const float* __restrict__ b1,
    const float* __restrict__ prm1, const float* __restrict__ prelu1,
    const float* __restrict__ w2, const float* __restrict__ b2,
    float* __restrict__ sig, float* __restrict__ part2)
{
  __shared__ float xb[1024];
  __shared__ float h1p[16*136];
  __shared__ float w2s[32*16*12];
  __shared__ float w1s[128];
  __shared__ float p1s[32];
  int tid = threadIdx.x; int b = blockIdx.x;
  *(float4*)&xb[tid*4] = *(const float4*)&x[b*1024 + tid*4];
  for (int i=tid; i<5120; i+=256) { int ff=i/10, k=i-ff*10; w2s[ff*12+k] = w2[i]; }
  if (tid<128) w1s[tid] = w1[tid];
  if (tid<32)  p1s[tid] = prm1[tid];
  float a1 = prelu1[0];
  __syncthreads();
#pragma unroll
  for (int r=0; r<8; ++r) {
    int o = tid + 256*r; int f = o>>7, t = o&127;
    float v = b1[f];
#pragma unroll
    for (int ch=0; ch<8; ++ch) v = fmaf(xb[ch*128+t], w1s[f*8+ch], v);
    v = fmaf(v, p1s[2*f], p1s[2*f+1]);
    v = (v>=0.f) ? v : a1*v;
    h1p[f*136 + t] = v;
  }
  __syncthreads();
  int f2 = tid>>3, wb = (tid&7)*8;
  float acc[8];
  float bb = b2[f2];
#pragma unroll
  for (int j=0;j<8;++j) acc[j]=bb;
  for (int f1=0; f1<16; ++f1) {
    const float* hrow = &h1p[f1*136 + 2*wb];
    float hw[24];
#pragma unroll
    for (int m=0;m<6;++m) *(float4*)&hw[m*4] = *(const float4*)&hrow[m*4];
    const float* wr = &w2s[(f2*16+f1)*12];
    float wk[10];
    *(float4*)&wk[0] = *(const float4*)&wr[0];
    *(float4*)&wk[4] = *(const float4*)&wr[4];
    wk[8]=wr[8]; wk[9]=wr[9];
#pragma unroll
    for (int j=0;j<8;++j)
#pragma unroll
      for (int k=0;k<10;++k) acc[j] = fmaf(hw[2*j+k], wk[k], acc[j]);
  }
  float s=0.f, q=0.f;
#pragma unroll
  for (int j=0;j<8;++j) {
    int w = wb+j;
    if (w < 60) { sig[b*1920 + f2*60 + w] = acc[j]; s += acc[j]; q = fmaf(acc[j],acc[j],q); }
  }
  s += __shfl_down(s,4,8); q += __shfl_down(q,4,8);
  s += __shfl_down(s,2,8); q += __shfl_down(q,2,8);
  s += __shfl_down(s,1,8); q += __shfl_down(q,1,8);
  if ((tid&7)==0) {
    part2[(size_t)b*64 + 2*f2]     = s;
    part2[(size_t)b*64 + 2*f2 + 1] = q;
  }
}

// ---------------- cosine table for 60-pt real-FFT ----------------
__global__ void k_costab(float* __restrict__ ct)
{
  int i = blockIdx.x*256 + threadIdx.x;
  if (i < 3600) {
    int k = i/60, n = i - k*60;
    int m = (k*n) % 60;
    ct[i] = cosf(0.104719755119659775f * (float)m);  // 2*pi/60
  }
}

// ---------------- bn2-apply + prelu (in-place sig) + 60-pt cos transform -> fft ----------------
__global__ __launch_bounds__(256) void k_sigfft(
    float* __restrict__ sig, float* __restrict__ fft,
    const float* __restrict__ prm2, const float* __restrict__ prelu2,
    const float* __restrict__ ctab)
{
  __shared__ float ct[3600];
  __shared__ float rowb[4*60];
  int tid = threadIdx.x;
  for (int i=tid; i<3600; i+=256) ct[i] = ctab[i];
  int r4 = tid>>6, lane = tid&63;
  int row = blockIdx.x*4 + r4;        // (b,c), 131072 rows
  int c = row & 31;
  float a2 = prelu2[0];
  float sc = prm2[2*c], sh = prm2[2*c+1];
  size_t base = (size_t)row*60;
  if (lane < 60) {
    float v = fmaf(sig[base+lane], sc, sh);
    v = (v>=0.f) ? v : a2*v;
    rowb[r4*60+lane] = v;
    sig[base+lane] = v;
  }
  __syncthreads();
  if (lane < 60) {
    float s = 0.f;
    const float* rb = &rowb[r4*60];
#pragma unroll 6
    for (int n=0; n<60; ++n) s = fmaf(rb[n], ct[n*60+lane], s);
    fft[base+lane] = s;
  }
}

// ---------------- fused bidirectional LSTM over sig+fft streams ----------------
// wave = one (sample, dir, branch); lane l: unit u=l&31, half=l>>5
// half0 owns gate rows {u (i), 64+u (g)}, half1 owns {32+u (f), 96+u (o)}
// weights PINNED register-resident (128 VGPR/lane); x,h broadcast from private LDS slice
__global__ __launch_bounds__(256,2) void k_lstm_fused(
    const float* __restrict__ sigA, const float* __restrict__ sigB,
    const float* __restrict__ fftA, const float* __restrict__ fftB,
    float* __restrict__ routA, float* __restrict__ routB,
    const float* __restrict__ wihf, const float* __restrict__ whhf,
    const float* __restrict__ bihf, const float* __restrict__ bhhf,
    const float* __restrict__ wihr, const float* __restrict__ whhr,
    const float* __restrict__ bihr, const float* __restrict__ bhhr)
{
  __shared__ float L[4][3904];     // per wave: XS[60][32] | XF[60][32] | H1[32] | H2[32]
  const int tid  = threadIdx.x;
  const int lane = tid & 63;
  const int w    = tid >> 6;
  const int u    = lane & 31;
  const int half = lane >> 5;
  const int s    = blockIdx.x*4 + w;
  const int dir  = blockIdx.y;
  const float* in1 = blockIdx.z ? sigB : sigA;
  const float* in2 = blockIdx.z ? fftB : fftA;
  float*       out = blockIdx.z ? routB : routA;
  const float* wih = dir ? wihr : wihf;
  const float* whh = dir ? whhr : whhf;
  const float* bih = dir ? bihr : bihf;
  const float* bhh = dir ? bhhr : bhhf;

  float* XS = &L[w][0];
  float* XF = &L[w][1920];
  float* H1 = &L[w][3840];
  float* H2 = &L[w][3872];

  // stage both x streams (coalesced float4), zero h
  for (int i = lane; i < 480; i += 64) {
    int t = i >> 3, q4 = (i & 7) * 4;
    *(float4*)&XS[t*32 + q4] = *(const float4*)&in1[(size_t)t*131072 + (size_t)s*32 + q4];
    *(float4*)&XF[t*32 + q4] = *(const float4*)&in2[(size_t)t*131072 + (size_t)s*32 + q4];
  }
  if (half == 0) { H1[u] = 0.f; H2[u] = 0.f; }

  // register-resident weights: rows rA, rB of wih and whh
  const int rA = half*32 + u;
  const int rB = 64 + half*32 + u;
  float4 wxA[8], wxB[8], whA[8], whB[8];
#pragma unroll
  for (int m=0; m<8; ++m) {
    wxA[m] = *(const float4*)&wih[rA*32 + m*4];
    wxB[m] = *(const float4*)&wih[rB*32 + m*4];
    whA[m] = *(const float4*)&whh[rA*32 + m*4];
    whB[m] = *(const float4*)&whh[rB*32 + m*4];
  }
  // opaque def: forbid rematerialization of the weight loads inside the loop
#pragma unroll
  for (int m=0; m<8; ++m) { PIN4(wxA[m]); PIN4(wxB[m]); PIN4(whA[m]); PIN4(whB[m]); }
  const float bA = bih[rA] + bhh[rA];
  const float bB = bih[rB] + bhh[rB];

  float c1 = 0.f, c2 = 0.f;
  const size_t obase = (size_t)s*64 + dir*32 + u;

  for (int q = 0; q < 60; ++q) {
    const int tt = dir ? (59 - q) : q;
    float a1A = bA, a1B = bB, a2A = bA, a2B = bB;
    const float* xs = &XS[tt*32];
    const float* xf = &XF[tt*32];
#pragma unroll
    for (int m=0; m<8; ++m) {
      float4 v1 = *(const float4*)&xs[m*4];
      float4 v2 = *(const float4*)&xf[m*4];
      a1A = dot4(v1, wxA[m], a1A); a1B = dot4(v1, wxB[m], a1B);
      a2A = dot4(v2, wxA[m], a2A); a2B = dot4(v2, wxB[m], a2B);
    }
#pragma unroll
    for (int m=0; m<8; ++m) {
      float4 v1 = *(const float4*)&H1[m*4];
      float4 v2 = *(const float4*)&H2[m*4];
      a1A = dot4(v1, whA[m], a1A); a1B = dot4(v1, whB[m], a1B);
      a2A = dot4(v2, whA[m], a2A); a2B = dot4(v2, whB[m], a2B);
    }
    // exchange across halves: half0 holds (i,g), half1 holds (f,o)
    float x1A = __shfl_xor(a1A, 32), x1B = __shfl_xor(a1B, 32);
    float x2A = __shfl_xor(a2A, 32), x2B = __shfl_xor(a2B, 32);
    float gi1 = half ? x1A : a1A, gf1 = half ? a1A : x1A;
    float gg1 = half ? x1B : a1B, go1 = half ? a1B : x1B;
    float gi2 = half ? x2A : a2A, gf2 = half ? a2A : x2A;
    float gg2 = half ? x2B : a2B, go2 = half ? a2B : x2B;
    c1 = sigf(gf1)*c1 + sigf(gi1)*tanhfast(gg1);
    float h1 = sigf(go1)*tanhfast(c1);
    c2 = sigf(gf2)*c2 + sigf(gi2)*tanhfast(gg2);
    float h2 = sigf(go2)*tanhfast(c2);
    if (half == 0) {
      H1[u] = h1; H2[u] = h2;
      out[(size_t)tt*262144 + obase] = h1 + h2;
    }
  }
}

// ---------------- bnf stats over (4096 rows x 3840 features) ----------------
__global__ __launch_bounds__(256) void k_bnfstats(const float* __restrict__ rb, float* __restrict__ acc)
{
  int col = blockIdx.x*256 + threadIdx.x;            // 0..3839
  size_t r0 = (size_t)blockIdx.y*256;
  const float* p = rb + r0*3840 + col;
  float s=0.f, q=0.f;
  for (int r=0; r<256; ++r) { float v = p[(size_t)r*3840]; s += v; q = fmaf(v,v,q); }
  atomicAdd(&acc[2*col], s); atomicAdd(&acc[2*col+1], q);
}

// ---------------- finalize for atomically-accumulated stats ----------------
__global__ void k_finalize_bn(const float* __restrict__ acc, const float* __restrict__ g,
                              const float* __restrict__ b, float* __restrict__ prm,
                              int C, float invN)
{
  int i = blockIdx.x*blockDim.x + threadIdx.x;
  if (i < C) {
    float m = acc[2*i]*invN;
    float v = acc[2*i+1]*invN - m*m;
    float sc = g[i] / sqrtf(v + EPS);
    prm[2*i]   = sc;
    prm[2*i+1] = fmaf(-m, sc, b[i]);
  }
}

// ---------------- bn1d-apply + correlation + final 5-tap conv ----------------
__global__ __launch_bounds__(64) void k_corr(
    const float* __restrict__ ra, const float* __restrict__ rb,
    const float* __restrict__ pfa, const float* __restrict__ pfb,
    const float* __restrict__ cw, const float* __restrict__ cb,
    float* __restrict__ dout)
{
  __shared__ float sxt[12], sxx[12], stt[12], cv[12];
  int lane = threadIdx.x; int r = blockIdx.x;
  if (lane < 12) { sxt[lane]=0.f; sxx[lane]=0.f; stt[lane]=0.f; }
  __syncthreads();
  const float* pa = ra + (size_t)r*3840;
  const float* pb = rb + (size_t)r*3840;
  float xt0=0,xx0=0,tt0=0, xt1=0,xx1=0,tt1=0, xt2=0,xx2=0,tt2=0;
  for (int i=0; i<60; i+=3) {
    { int fe = lane + 64*i;
      float a = fmaf(pa[fe], pfa[2*fe], pfa[2*fe+1]);
      float b = fmaf(pb[fe], pfb[2*fe], pfb[2*fe+1]);
      xt0 = fmaf(a,b,xt0); xx0 = fmaf(a,a,xx0); tt0 = fmaf(b,b,tt0); }
    { int fe = lane + 64*(i+1);
      float a = fmaf(pa[fe], pfa[2*fe], pfa[2*fe+1]);
      float b = fmaf(pb[fe], pfb[2*fe], pfb[2*fe+1]);
      xt1 = fmaf(a,b,xt1); xx1 = fmaf(a,a,xx1); tt1 = fmaf(b,b,tt1); }
    { int fe = lane + 64*(i+2);
      float a = fmaf(pa[fe], pfa[2*fe], pfa[2*fe+1]);
      float b = fmaf(pb[fe], pfb[2*fe], pfb[2*fe+1]);
      xt2 = fmaf(a,b,xt2); xx2 = fmaf(a,a,xx2); tt2 = fmaf(b,b,tt2); }
  }
  int c0 = lane % 12;
  int c1 = (c0+4) % 12;
  int c2 = (c0+8) % 12;
  atomicAdd(&sxt[c0], xt0); atomicAdd(&sxx[c0], xx0); atomicAdd(&stt[c0], tt0);
  atomicAdd(&sxt[c1], xt1); atomicAdd(&sxx[c1], xx1); atomicAdd(&stt[c1], tt1);
  atomicAdd(&sxt[c2], xt2); atomicAdd(&sxx[c2], xx2); atomicAdd(&stt[c2], tt2);
  __syncthreads();
  if (lane < 12) {
    float corr = sxt[lane] / sqrtf(stt[lane]) / sqrtf(sxx[lane]);
    cv[lane] = corr;
    dout[49152 + r*12 + lane] = corr;
  }
  __syncthreads();
  if (lane < 12) {
    float o = cb[0];
#pragma unroll
    for (int k=0; k<5; ++k) { int j = lane + k - 2; if (j>=0 && j<12) o = fmaf(cv[j], cw[k], o); }
    dout[r*12 + lane] = o;
  }
}

// ---------------- host ----------------
extern "C" void kernel_launch(void* const* d_in, const int* in_sizes, int n_in,
                              void* d_out, int out_size, void* d_ws, size_t ws_size,
                              hipStream_t stream)
{
  const float* x    = (const float*)d_in[0];
  const float* tpl  = (const float*)d_in[1];
  const float* w1   = (const float*)d_in[2];
  const float* b1   = (const float*)d_in[3];
  const float* g1   = (const float*)d_in[4];
  const float* bb1  = (const float*)d_in[5];
  const float* p1   = (const float*)d_in[6];
  const float* w2   = (const float*)d_in[7];
  const float* b2   = (const float*)d_in[8];
  const float* g2   = (const float*)d_in[9];
  const float* bb2  = (const float*)d_in[10];
  const float* p2   = (const float*)d_in[11];
  const float* wihf = (const float*)d_in[12];
  const float* whhf = (const float*)d_in[13];
  const float* bihf = (const float*)d_in[14];
  const float* bhhf = (const float*)d_in[15];
  const float* wihr = (const float*)d_in[16];
  const float* whhr = (const float*)d_in[17];
  const float* bihr = (const float*)d_in[18];
  const float* bhhr = (const float*)d_in[19];
  const float* gf   = (const float*)d_in[20];
  const float* bf   = (const float*)d_in[21];
  const float* cw   = (const float*)d_in[22];
  const float* cb   = (const float*)d_in[23];
  float* W   = (float*)d_ws;
  float* out = (float*)d_out;

  // small scratch (float offsets)
  constexpr size_t PRM1A=64, PRM1B=96, PRM2A=256, PRM2B=320;
  constexpr size_t ACCFA=512, ACCFB=8192, PRMFA=15872, PRMFB=23552, CTAB=31232;
  constexpr size_t P1P=35072;               // 256*32
  constexpr size_t P2P=43264;               // 4096*64
  constexpr size_t SIGSZ = 7864320, RSZ = 15728640;
  constexpr size_t BIG0 = 307200;
  // fast layout: sigA | fftA | sigB | fftB | rbufA | rbufB
  constexpr size_t F_SIGA=BIG0, F_FFTA=F_SIGA+SIGSZ, F_SIGB=F_FFTA+SIGSZ, F_FFTB=F_SIGB+SIGSZ;
  constexpr size_t F_RBUFA=F_FFTB+SIGSZ, F_RBUFB=F_RBUFA+RSZ;
  constexpr size_t F_TOTAL=(F_RBUFB+RSZ)*sizeof(float);
  // sequential layout: sig | fft | rbufA | rbufB
  constexpr size_t S_SIG=BIG0, S_FFT=S_SIG+SIGSZ, S_RBUFA=S_FFT+SIGSZ, S_RBUFB=S_RBUFA+RSZ;

  const bool fast = ws_size >= F_TOTAL;

  hipMemsetAsync(W, 0, 65536, stream);               // zero bnf stat accumulators
  k_costab<<<15,256,0,stream>>>(W+CTAB);

  for (int br=0; br<2; ++br) {
    const float* xin  = br ? tpl : x;
    float* prm1 = W + (br ? PRM1B : PRM1A);
    float* prm2 = W + (br ? PRM2B : PRM2A);
    float* sig  = W + (fast ? (br ? F_SIGB : F_SIGA) : S_SIG);
    float* fft  = W + (fast ? (br ? F_FFTB : F_FFTA) : S_FFT);
    float* rbuf = W + (fast ? (br ? F_RBUFB : F_RBUFA) : (br ? S_RBUFB : S_RBUFA));
    k_conv1_stats<<<256,256,0,stream>>>(xin, w1, b1, W+P1P);
    k_reduce_finalize<<<16,256,0,stream>>>(W+P1P, 256, 16, g1, bb1, prm1, 1.f/524288.f);
    k_conv2<<<4096,256,0,stream>>>(xin, w1, b1, prm1, p1, w2, b2, sig, W+P2P);
    k_reduce_finalize<<<32,256,0,stream>>>(W+P2P, 4096, 32, g2, bb2, prm2, 1.f/245760.f);
    k_sigfft<<<32768,256,0,stream>>>(sig, fft, prm2, p2, W+CTAB);
    if (!fast) {
      // per-branch fused LSTM (z-grid 1, A-pointers only)
      k_lstm_fused<<<dim3(1024,2,1),256,0,stream>>>(sig, sig, fft, fft, rbuf, rbuf,
                                                    wihf,whhf,bihf,bhhf, wihr,whhr,bihr,bhhr);
    }
  }

  float* rbufA = W + (fast ? F_RBUFA : S_RBUFA);
  float* rbufB = W + (fast ? F_RBUFB : S_RBUFB);

  if (fast) {
    k_lstm_fused<<<dim3(1024,2,2),256,0,stream>>>(W+F_SIGA, W+F_SIGB, W+F_FFTA, W+F_FFTB,
                                                  rbufA, rbufB,
                                                  wihf,whhf,bihf,bhhf, wihr,whhr,bihr,bhhr);
  }

  k_bnfstats<<<dim3(15,16),256,0,stream>>>(rbufA, W+ACCFA);
  k_bnfstats<<<dim3(15,16),256,0,stream>>>(rbufB, W+ACCFB);
  k_finalize_bn<<<15,256,0,stream>>>(W+ACCFA, gf, bf, W+PRMFA, 3840, 1.f/4096.f);
  k_finalize_bn<<<15,256,0,stream>>>(W+ACCFB, gf, bf, W+PRMFB, 3840, 1.f/4096.f);

  k_corr<<<4096,64,0,stream>>>(rbufA, rbufB, W+PRMFA, W+PRMFB, cw, cb, out);
}

// Round 6
// 1018.813 us; speedup vs baseline: 6.6105x; 1.0305x over previous
//
#include <hip/hip_runtime.h>
#include <math.h>

#define EPS 1e-5f

__device__ __forceinline__ float fast_rcp(float x){ return __builtin_amdgcn_rcpf(x); }
__device__ __forceinline__ float sigf(float x){ return fast_rcp(1.0f + __expf(-x)); }
__device__ __forceinline__ float tanhfast(float x){ return fmaf(2.0f, fast_rcp(1.0f + __expf(-2.0f*x)), -1.0f); }
__device__ __forceinline__ float dot4(float4 a, float4 b, float c){
  return fmaf(a.w,b.w, fmaf(a.z,b.z, fmaf(a.y,b.y, fmaf(a.x,b.x, c))));
}

// ---------------- conv1 + bn1 partial stats: 256 blocks, register+LDS reduce ----------------
__global__ __launch_bounds__(256) void k_conv1_stats(
    const float* __restrict__ x, const float* __restrict__ w1,
    const float* __restrict__ b1, float* __restrict__ part)
{
  __shared__ float red[4][32];
  float s[16], q[16];
#pragma unroll
  for (int f=0; f<16; ++f) { s[f]=0.f; q[f]=0.f; }
  float w1r[128];
#pragma unroll
  for (int i=0; i<128; ++i) w1r[i] = w1[i];
  float b1r[16];
#pragma unroll
  for (int f=0; f<16; ++f) b1r[f] = b1[f];
  const int tid = threadIdx.x;
  for (int iter=0; iter<8; ++iter) {
    int n = blockIdx.x*2048 + iter*256 + tid;      // (b,t), 524288 total
    int b = n >> 7, t = n & 127;
    const float* xb = x + b*1024 + t;
    float xv[8];
#pragma unroll
    for (int ch=0; ch<8; ++ch) xv[ch] = xb[ch*128];
#pragma unroll
    for (int f=0; f<16; ++f) {
      float v = b1r[f];
#pragma unroll
      for (int ch=0; ch<8; ++ch) v = fmaf(xv[ch], w1r[f*8+ch], v);
      s[f] += v; q[f] = fmaf(v,v,q[f]);
    }
  }
#pragma unroll
  for (int f=0; f<16; ++f) {
#pragma unroll
    for (int d=32; d>0; d>>=1) { s[f] += __shfl_down(s[f],d); q[f] += __shfl_down(q[f],d); }
  }
  const int lane = tid & 63, wv = tid >> 6;
  if (lane == 0) {
#pragma unroll
    for (int f=0; f<16; ++f) { red[wv][2*f] = s[f]; red[wv][2*f+1] = q[f]; }
  }
  __syncthreads();
  if (tid < 32) {
    float v = red[0][tid] + red[1][tid] + red[2][tid] + red[3][tid];
    part[blockIdx.x*32 + tid] = v;
  }
}

// ---------------- reduce partials + finalize scale/shift ----------------
__global__ __launch_bounds__(256) void k_reduce_finalize(
    const float* __restrict__ part, int nblk, int C,
    const float* __restrict__ g, const float* __restrict__ b,
    float* __restrict__ prm, float invN)
{
  __shared__ float red[4][2];
  const int c = blockIdx.x;
  const int tid = threadIdx.x;
  float s=0.f, q=0.f;
  for (int i=tid; i<nblk; i+=256) {
    s += part[(size_t)i*2*C + 2*c];
    q += part[(size_t)i*2*C + 2*c + 1];
  }
#pragma unroll
  for (int d=32; d>0; d>>=1) { s += __shfl_down(s,d); q += __shfl_down(q,d); }
  const int lane = tid & 63, wv = tid >> 6;
  if (lane==0) { red[wv][0]=s; red[wv][1]=q; }
  __syncthreads();
  if (tid==0) {
    s = red[0][0]+red[1][0]+red[2][0]+red[3][0];
    q = red[0][1]+red[1][1]+red[2][1]+red[3][1];
    float m = s*invN;
    float v = q*invN - m*m;
    float sc = g[c] / sqrtf(v + EPS);
    prm[2*c]   = sc;
    prm[2*c+1] = fmaf(-m, sc, b[c]);
  }
}

// ---------------- conv1(recompute)+bn1+prelu -> conv2 -> raw out + bn2 partials ----------------
__global__ __launch_bounds__(256) void k_conv2(
    const float* __restrict__ x,
    const float* __restrict__ w1, const float* __restrict__ b1,
    const float* __restrict__ prm1, const float* __restrict__ prelu1,
    const float* __restrict__ w2, const float* __restrict__ b2,
    float* __restrict__ sig, float* __restrict__ part2)
{
  __shared__ float xb[1024];
  __shared__ float h1p[16*136];
  __shared__ float w2s[32*16*12];
  __shared__ float w1s[128];
  __shared__ float p1s[32];
  int tid = threadIdx.x; int b = blockIdx.x;
  *(float4*)&xb[tid*4] = *(const float4*)&x[b*1024 + tid*4];
  for (int i=tid; i<5120; i+=256) { int ff=i/10, k=i-ff*10; w2s[ff*12+k] = w2[i]; }
  if (tid<128) w1s[tid] = w1[tid];
  if (tid<32)  p1s[tid] = prm1[tid];
  float a1 = prelu1[0];
  __syncthreads();
#pragma unroll
  for (int r=0; r<8; ++r) {
    int o = tid + 256*r; int f = o>>7, t = o&127;
    float v = b1[f];
#pragma unroll
    for (int ch=0; ch<8; ++ch) v = fmaf(xb[ch*128+t], w1s[f*8+ch], v);
    v = fmaf(v, p1s[2*f], p1s[2*f+1]);
    v = (v>=0.f) ? v : a1*v;
    h1p[f*136 + t] = v;
  }
  __syncthreads();
  int f2 = tid>>3, wb = (tid&7)*8;
  float acc[8];
  float bb = b2[f2];
#pragma unroll
  for (int j=0;j<8;++j) acc[j]=bb;
  for (int f1=0; f1<16; ++f1) {
    const float* hrow = &h1p[f1*136 + 2*wb];
    float hw[24];
#pragma unroll
    for (int m=0;m<6;++m) *(float4*)&hw[m*4] = *(const float4*)&hrow[m*4];
    const float* wr = &w2s[(f2*16+f1)*12];
    float wk[10];
    *(float4*)&wk[0] = *(const float4*)&wr[0];
    *(float4*)&wk[4] = *(const float4*)&wr[4];
    wk[8]=wr[8]; wk[9]=wr[9];
#pragma unroll
    for (int j=0;j<8;++j)
#pragma unroll
      for (int k=0;k<10;++k) acc[j] = fmaf(hw[2*j+k], wk[k], acc[j]);
  }
  float s=0.f, q=0.f;
#pragma unroll
  for (int j=0;j<8;++j) {
    int w = wb+j;
    if (w < 60) { sig[b*1920 + f2*60 + w] = acc[j]; s += acc[j]; q = fmaf(acc[j],acc[j],q); }
  }
  s += __shfl_down(s,4,8); q += __shfl_down(q,4,8);
  s += __shfl_down(s,2,8); q += __shfl_down(q,2,8);
  s += __shfl_down(s,1,8); q += __shfl_down(q,1,8);
  if ((tid&7)==0) {
    part2[(size_t)b*64 + 2*f2]     = s;
    part2[(size_t)b*64 + 2*f2 + 1] = q;
  }
}

// ---------------- cosine table for 60-pt real-FFT ----------------
__global__ void k_costab(float* __restrict__ ct)
{
  int i = blockIdx.x*256 + threadIdx.x;
  if (i < 3600) {
    int k = i/60, n = i - k*60;
    int m = (k*n) % 60;
    ct[i] = cosf(0.104719755119659775f * (float)m);  // 2*pi/60
  }
}

// ---------------- bn2-apply + prelu (in-place sig) + 60-pt cos transform -> fft ----------------
// 16 rows/block: cos-table staged once per block, 4 row-groups processed per wave
__global__ __launch_bounds__(256) void k_sigfft(
    float* __restrict__ sig, float* __restrict__ fft,
    const float* __restrict__ prm2, const float* __restrict__ prelu2,
    const float* __restrict__ ctab)
{
  __shared__ float ct[3600];
  __shared__ float rowb[4][4][60];
  int tid = threadIdx.x;
  for (int i=tid; i<3600; i+=256) ct[i] = ctab[i];
  int r4 = tid>>6, lane = tid&63;
  float a2 = prelu2[0];
  __syncthreads();
#pragma unroll
  for (int it=0; it<4; ++it) {
    int row = blockIdx.x*16 + it*4 + r4;   // (b,c), 131072 rows
    int c = row & 31;
    float sc = prm2[2*c], sh = prm2[2*c+1];
    size_t base = (size_t)row*60;
    if (lane < 60) {
      float v = fmaf(sig[base+lane], sc, sh);
      v = (v>=0.f) ? v : a2*v;
      rowb[it][r4][lane] = v;
      sig[base+lane] = v;
    }
    // same-wave LDS write->read: compiler inserts lgkmcnt wait; no barrier needed
    if (lane < 60) {
      float s = 0.f;
      const float* rb = rowb[it][r4];
#pragma unroll 6
      for (int n=0; n<60; ++n) s = fmaf(rb[n], ct[n*60+lane], s);
      fft[base+lane] = s;
    }
  }
}

// ---------------- fused bidirectional LSTM over sig+fft streams ----------------
// wave = one (sample, dir, branch); lane l: unit u=l&31, half=l>>5
// half0 owns gate rows {u (i), 64+u (g)}, half1 owns {32+u (f), 96+u (o)}
// launch_bounds(256,1): allow up to 512 VGPR so weights stay in architected VGPRs
// (occupancy is LDS-bound at 2 blocks/CU regardless)
__global__ __launch_bounds__(256,1) void k_lstm_fused(
    const float* __restrict__ sigA, const float* __restrict__ sigB,
    const float* __restrict__ fftA, const float* __restrict__ fftB,
    float* __restrict__ routA, float* __restrict__ routB,
    const float* __restrict__ wihf, const float* __restrict__ whhf,
    const float* __restrict__ bihf, const float* __restrict__ bhhf,
    const float* __restrict__ wihr, const float* __restrict__ whhr,
    const float* __restrict__ bihr, const float* __restrict__ bhhr)
{
  __shared__ float L[4][3904];     // per wave: XS[60][32] | XF[60][32] | H1[32] | H2[32]
  const int tid  = threadIdx.x;
  const int lane = tid & 63;
  const int w    = tid >> 6;
  const int u    = lane & 31;
  const int half = lane >> 5;
  const int s    = blockIdx.x*4 + w;
  const int dir  = blockIdx.y;
  const float* in1 = blockIdx.z ? sigB : sigA;
  const float* in2 = blockIdx.z ? fftB : fftA;
  float*       out = blockIdx.z ? routB : routA;
  const float* wih = dir ? wihr : wihf;
  const float* whh = dir ? whhr : whhf;
  const float* bih = dir ? bihr : bihf;
  const float* bhh = dir ? bhhr : bhhf;

  float* XS = &L[w][0];
  float* XF = &L[w][1920];
  float* H1 = &L[w][3840];
  float* H2 = &L[w][3872];

  // stage both x streams (coalesced float4), zero h
  for (int i = lane; i < 480; i += 64) {
    int t = i >> 3, q4 = (i & 7) * 4;
    *(float4*)&XS[t*32 + q4] = *(const float4*)&in1[(size_t)t*131072 + (size_t)s*32 + q4];
    *(float4*)&XF[t*32 + q4] = *(const float4*)&in2[(size_t)t*131072 + (size_t)s*32 + q4];
  }
  if (half == 0) { H1[u] = 0.f; H2[u] = 0.f; }

  // register-resident weights: rows rA, rB of wih and whh
  const int rA = half*32 + u;
  const int rB = 64 + half*32 + u;
  float4 wxA[8], wxB[8], whA[8], whB[8];
#pragma unroll
  for (int m=0; m<8; ++m) {
    wxA[m] = *(const float4*)&wih[rA*32 + m*4];
    wxB[m] = *(const float4*)&wih[rB*32 + m*4];
    whA[m] = *(const float4*)&whh[rA*32 + m*4];
    whB[m] = *(const float4*)&whh[rB*32 + m*4];
  }
  const float bA = bih[rA] + bhh[rA];
  const float bB = bih[rB] + bhh[rB];

  float c1 = 0.f, c2 = 0.f;
  const size_t obase = (size_t)s*64 + dir*32 + u;

  for (int q = 0; q < 60; ++q) {
    const int tt = dir ? (59 - q) : q;
    float a1A = bA, a1B = bB, a2A = bA, a2B = bB;
    const float* xs = &XS[tt*32];
    const float* xf = &XF[tt*32];
#pragma unroll
    for (int m=0; m<8; ++m) {
      float4 v1 = *(const float4*)&xs[m*4];
      float4 v2 = *(const float4*)&xf[m*4];
      a1A = dot4(v1, wxA[m], a1A); a1B = dot4(v1, wxB[m], a1B);
      a2A = dot4(v2, wxA[m], a2A); a2B = dot4(v2, wxB[m], a2B);
    }
#pragma unroll
    for (int m=0; m<8; ++m) {
      float4 v1 = *(const float4*)&H1[m*4];
      float4 v2 = *(const float4*)&H2[m*4];
      a1A = dot4(v1, whA[m], a1A); a1B = dot4(v1, whB[m], a1B);
      a2A = dot4(v2, whA[m], a2A); a2B = dot4(v2, whB[m], a2B);
    }
    // exchange across halves: half0 holds (i,g), half1 holds (f,o)
    float x1A = __shfl_xor(a1A, 32), x1B = __shfl_xor(a1B, 32);
    float x2A = __shfl_xor(a2A, 32), x2B = __shfl_xor(a2B, 32);
    float gi1 = half ? x1A : a1A, gf1 = half ? a1A : x1A;
    float gg1 = half ? x1B : a1B, go1 = half ? a1B : x1B;
    float gi2 = half ? x2A : a2A, gf2 = half ? a2A : x2A;
    float gg2 = half ? x2B : a2B, go2 = half ? a2B : x2B;
    c1 = sigf(gf1)*c1 + sigf(gi1)*tanhfast(gg1);
    float h1 = sigf(go1)*tanhfast(c1);
    c2 = sigf(gf2)*c2 + sigf(gi2)*tanhfast(gg2);
    float h2 = sigf(go2)*tanhfast(c2);
    if (half == 0) {
      H1[u] = h1; H2[u] = h2;
      out[(size_t)tt*262144 + obase] = h1 + h2;
    }
  }
}

// ---------------- bnf stats over (4096 rows x 3840 features) ----------------
__global__ __launch_bounds__(256) void k_bnfstats(const float* __restrict__ rb, float* __restrict__ acc)
{
  int col = blockIdx.x*256 + threadIdx.x;            // 0..3839
  size_t r0 = (size_t)blockIdx.y*256;
  const float* p = rb + r0*3840 + col;
  float s=0.f, q=0.f;
  for (int r=0; r<256; ++r) { float v = p[(size_t)r*3840]; s += v; q = fmaf(v,v,q); }
  atomicAdd(&acc[2*col], s); atomicAdd(&acc[2*col+1], q);
}

// ---------------- finalize for atomically-accumulated stats ----------------
__global__ void k_finalize_bn(const float* __restrict__ acc, const float* __restrict__ g,
                              const float* __restrict__ b, float* __restrict__ prm,
                              int C, float invN)
{
  int i = blockIdx.x*blockDim.x + threadIdx.x;
  if (i < C) {
    float m = acc[2*i]*invN;
    float v = acc[2*i+1]*invN - m*m;
    float sc = g[i] / sqrtf(v + EPS);
    prm[2*i]   = sc;
    prm[2*i+1] = fmaf(-m, sc, b[i]);
  }
}

// ---------------- bn1d-apply + correlation + final 5-tap conv ----------------
__global__ __launch_bounds__(64) void k_corr(
    const float* __restrict__ ra, const float* __restrict__ rb,
    const float* __restrict__ pfa, const float* __restrict__ pfb,
    const float* __restrict__ cw, const float* __restrict__ cb,
    float* __restrict__ dout)
{
  __shared__ float sxt[12], sxx[12], stt[12], cv[12];
  int lane = threadIdx.x; int r = blockIdx.x;
  if (lane < 12) { sxt[lane]=0.f; sxx[lane]=0.f; stt[lane]=0.f; }
  __syncthreads();
  const float* pa = ra + (size_t)r*3840;
  const float* pb = rb + (size_t)r*3840;
  float xt0=0,xx0=0,tt0=0, xt1=0,xx1=0,tt1=0, xt2=0,xx2=0,tt2=0;
  for (int i=0; i<60; i+=3) {
    { int fe = lane + 64*i;
      float a = fmaf(pa[fe], pfa[2*fe], pfa[2*fe+1]);
      float b = fmaf(pb[fe], pfb[2*fe], pfb[2*fe+1]);
      xt0 = fmaf(a,b,xt0); xx0 = fmaf(a,a,xx0); tt0 = fmaf(b,b,tt0); }
    { int fe = lane + 64*(i+1);
      float a = fmaf(pa[fe], pfa[2*fe], pfa[2*fe+1]);
      float b = fmaf(pb[fe], pfb[2*fe], pfb[2*fe+1]);
      xt1 = fmaf(a,b,xt1); xx1 = fmaf(a,a,xx1); tt1 = fmaf(b,b,tt1); }
    { int fe = lane + 64*(i+2);
      float a = fmaf(pa[fe], pfa[2*fe], pfa[2*fe+1]);
      float b = fmaf(pb[fe], pfb[2*fe], pfb[2*fe+1]);
      xt2 = fmaf(a,b,xt2); xx2 = fmaf(a,a,xx2); tt2 = fmaf(b,b,tt2); }
  }
  int c0 = lane % 12;
  int c1 = (c0+4) % 12;
  int c2 = (c0+8) % 12;
  atomicAdd(&sxt[c0], xt0); atomicAdd(&sxx[c0], xx0); atomicAdd(&stt[c0], tt0);
  atomicAdd(&sxt[c1], xt1); atomicAdd(&sxx[c1], xx1); atomicAdd(&stt[c1], tt1);
  atomicAdd(&sxt[c2], xt2); atomicAdd(&sxx[c2], xx2); atomicAdd(&stt[c2], tt2);
  __syncthreads();
  if (lane < 12) {
    float corr = sxt[lane] / sqrtf(stt[lane]) / sqrtf(sxx[lane]);
    cv[lane] = corr;
    dout[49152 + r*12 + lane] = corr;
  }
  __syncthreads();
  if (lane < 12) {
    float o = cb[0];
#pragma unroll
    for (int k=0; k<5; ++k) { int j = lane + k - 2; if (j>=0 && j<12) o = fmaf(cv[j], cw[k], o); }
    dout[r*12 + lane] = o;
  }
}

// ---------------- host ----------------
extern "C" void kernel_launch(void* const* d_in, const int* in_sizes, int n_in,
                              void* d_out, int out_size, void* d_ws, size_t ws_size,
                              hipStream_t stream)
{
  const float* x    = (const float*)d_in[0];
  const float* tpl  = (const float*)d_in[1];
  const float* w1   = (const float*)d_in[2];
  const float* b1   = (const float*)d_in[3];
  const float* g1   = (const float*)d_in[4];
  const float* bb1  = (const float*)d_in[5];
  const float* p1   = (const float*)d_in[6];
  const float* w2   = (const float*)d_in[7];
  const float* b2   = (const float*)d_in[8];
  const float* g2   = (const float*)d_in[9];
  const float* bb2  = (const float*)d_in[10];
  const float* p2   = (const float*)d_in[11];
  const float* wihf = (const float*)d_in[12];
  const float* whhf = (const float*)d_in[13];
  const float* bihf = (const float*)d_in[14];
  const float* bhhf = (const float*)d_in[15];
  const float* wihr = (const float*)d_in[16];
  const float* whhr = (const float*)d_in[17];
  const float* bihr = (const float*)d_in[18];
  const float* bhhr = (const float*)d_in[19];
  const float* gf   = (const float*)d_in[20];
  const float* bf   = (const float*)d_in[21];
  const float* cw   = (const float*)d_in[22];
  const float* cb   = (const float*)d_in[23];
  float* W   = (float*)d_ws;
  float* out = (float*)d_out;

  // small scratch (float offsets)
  constexpr size_t PRM1A=64, PRM1B=96, PRM2A=256, PRM2B=320;
  constexpr size_t ACCFA=512, ACCFB=8192, PRMFA=15872, PRMFB=23552, CTAB=31232;
  constexpr size_t P1P=35072;               // 256*32
  constexpr size_t P2P=43264;               // 4096*64
  constexpr size_t SIGSZ = 7864320, RSZ = 15728640;
  constexpr size_t BIG0 = 307200;
  // fast layout: sigA | fftA | sigB | fftB | rbufA | rbufB
  constexpr size_t F_SIGA=BIG0, F_FFTA=F_SIGA+SIGSZ, F_SIGB=F_FFTA+SIGSZ, F_FFTB=F_SIGB+SIGSZ;
  constexpr size_t F_RBUFA=F_FFTB+SIGSZ, F_RBUFB=F_RBUFA+RSZ;
  constexpr size_t F_TOTAL=(F_RBUFB+RSZ)*sizeof(float);
  // sequential layout: sig | fft | rbufA | rbufB
  constexpr size_t S_SIG=BIG0, S_FFT=S_SIG+SIGSZ, S_RBUFA=S_FFT+SIGSZ, S_RBUFB=S_RBUFA+RSZ;

  const bool fast = ws_size >= F_TOTAL;

  hipMemsetAsync(W, 0, 65536, stream);               // zero bnf stat accumulators
  k_costab<<<15,256,0,stream>>>(W+CTAB);

  for (int br=0; br<2; ++br) {
    const float* xin  = br ? tpl : x;
    float* prm1 = W + (br ? PRM1B : PRM1A);
    float* prm2 = W + (br ? PRM2B : PRM2A);
    float* sig  = W + (fast ? (br ? F_SIGB : F_SIGA) : S_SIG);
    float* fft  = W + (fast ? (br ? F_FFTB : F_FFTA) : S_FFT);
    float* rbuf = W + (fast ? (br ? F_RBUFB : F_RBUFA) : (br ? S_RBUFB : S_RBUFA));
    k_conv1_stats<<<256,256,0,stream>>>(xin, w1, b1, W+P1P);
    k_reduce_finalize<<<16,256,0,stream>>>(W+P1P, 256, 16, g1, bb1, prm1, 1.f/524288.f);
    k_conv2<<<4096,256,0,stream>>>(xin, w1, b1, prm1, p1, w2, b2, sig, W+P2P);
    k_reduce_finalize<<<32,256,0,stream>>>(W+P2P, 4096, 32, g2, bb2, prm2, 1.f/245760.f);
    k_sigfft<<<8192,256,0,stream>>>(sig, fft, prm2, p2, W+CTAB);
    if (!fast) {
      // per-branch fused LSTM (z-grid 1, A-pointers only)
      k_lstm_fused<<<dim3(1024,2,1),256,0,stream>>>(sig, sig, fft, fft, rbuf, rbuf,
                                                    wihf,whhf,bihf,bhhf, wihr,whhr,bihr,bhhr);
    }
  }

  float* rbufA = W + (fast ? F_RBUFA : S_RBUFA);
  float* rbufB = W + (fast ? F_RBUFB : S_RBUFB);

  if (fast) {
    k_lstm_fused<<<dim3(1024,2,2),256,0,stream>>>(W+F_SIGA, W+F_SIGB, W+F_FFTA, W+F_FFTB,
                                                  rbufA, rbufB,
                                                  wihf,whhf,bihf,bhhf, wihr,whhr,bihr,bhhr);
  }

  k_bnfstats<<<dim3(15,16),256,0,stream>>>(rbufA, W+ACCFA);
  k_bnfstats<<<dim3(15,16),256,0,stream>>>(rbufB, W+ACCFB);
  k_finalize_bn<<<15,256,0,stream>>>(W+ACCFA, gf, bf, W+PRMFA, 3840, 1.f/4096.f);
  k_finalize_bn<<<15,256,0,stream>>>(W+ACCFB, gf, bf, W+PRMFB, 3840, 1.f/4096.f);

  k_corr<<<4096,64,0,stream>>>(rbufA, rbufB, W+PRMFA, W+PRMFB, cw, cb, out);
}

// Round 7
// 688.430 us; speedup vs baseline: 9.7829x; 1.4799x over previous
//
#include <hip/hip_runtime.h>
#include <math.h>

#define EPS 1e-5f

typedef __attribute__((ext_vector_type(8))) short bf16x8;
typedef __attribute__((ext_vector_type(4))) float f32x4;
typedef __attribute__((ext_vector_type(4))) short s16x4;

__device__ __forceinline__ float fast_rcp(float x){ return __builtin_amdgcn_rcpf(x); }
__device__ __forceinline__ float sigf(float x){ return fast_rcp(1.0f + __expf(-x)); }
__device__ __forceinline__ float tanhfast(float x){ return fmaf(2.0f, fast_rcp(1.0f + __expf(-2.0f*x)), -1.0f); }
__device__ __forceinline__ float dot4(float4 a, float4 b, float c){
  return fmaf(a.w,b.w, fmaf(a.z,b.z, fmaf(a.y,b.y, fmaf(a.x,b.x, c))));
}
__device__ __forceinline__ short f2bf(float f){
  unsigned u = __float_as_uint(f);
  u = (u + 0x7FFFu + ((u>>16)&1u)) >> 16;
  return (short)u;
}
__device__ __forceinline__ float bf2f(short s){
  return __uint_as_float(((unsigned)(unsigned short)s) << 16);
}

// ---------------- conv1 + bn1 partial stats ----------------
__global__ __launch_bounds__(256) void k_conv1_stats(
    const float* __restrict__ x, const float* __restrict__ w1,
    const float* __restrict__ b1, float* __restrict__ part)
{
  __shared__ float red[4][32];
  float s[16], q[16];
#pragma unroll
  for (int f=0; f<16; ++f) { s[f]=0.f; q[f]=0.f; }
  float w1r[128];
#pragma unroll
  for (int i=0; i<128; ++i) w1r[i] = w1[i];
  float b1r[16];
#pragma unroll
  for (int f=0; f<16; ++f) b1r[f] = b1[f];
  const int tid = threadIdx.x;
  for (int iter=0; iter<8; ++iter) {
    int n = blockIdx.x*2048 + iter*256 + tid;
    int b = n >> 7, t = n & 127;
    const float* xb = x + b*1024 + t;
    float xv[8];
#pragma unroll
    for (int ch=0; ch<8; ++ch) xv[ch] = xb[ch*128];
#pragma unroll
    for (int f=0; f<16; ++f) {
      float v = b1r[f];
#pragma unroll
      for (int ch=0; ch<8; ++ch) v = fmaf(xv[ch], w1r[f*8+ch], v);
      s[f] += v; q[f] = fmaf(v,v,q[f]);
    }
  }
#pragma unroll
  for (int f=0; f<16; ++f) {
#pragma unroll
    for (int d=32; d>0; d>>=1) { s[f] += __shfl_down(s[f],d); q[f] += __shfl_down(q[f],d); }
  }
  const int lane = tid & 63, wv = tid >> 6;
  if (lane == 0) {
#pragma unroll
    for (int f=0; f<16; ++f) { red[wv][2*f] = s[f]; red[wv][2*f+1] = q[f]; }
  }
  __syncthreads();
  if (tid < 32) {
    float v = red[0][tid] + red[1][tid] + red[2][tid] + red[3][tid];
    part[blockIdx.x*32 + tid] = v;
  }
}

// ---------------- reduce partials + finalize scale/shift ----------------
__global__ __launch_bounds__(256) void k_reduce_finalize(
    const float* __restrict__ part, int nblk, int C,
    const float* __restrict__ g, const float* __restrict__ b,
    float* __restrict__ prm, float invN)
{
  __shared__ float red[4][2];
  const int c = blockIdx.x;
  const int tid = threadIdx.x;
  float s=0.f, q=0.f;
  for (int i=tid; i<nblk; i+=256) {
    s += part[(size_t)i*2*C + 2*c];
    q += part[(size_t)i*2*C + 2*c + 1];
  }
#pragma unroll
  for (int d=32; d>0; d>>=1) { s += __shfl_down(s,d); q += __shfl_down(q,d); }
  const int lane = tid & 63, wv = tid >> 6;
  if (lane==0) { red[wv][0]=s; red[wv][1]=q; }
  __syncthreads();
  if (tid==0) {
    s = red[0][0]+red[1][0]+red[2][0]+red[3][0];
    q = red[0][1]+red[1][1]+red[2][1]+red[3][1];
    float m = s*invN;
    float v = q*invN - m*m;
    float sc = g[c] / sqrtf(v + EPS);
    prm[2*c]   = sc;
    prm[2*c+1] = fmaf(-m, sc, b[c]);
  }
}

// ---------------- conv1(recompute)+bn1+prelu -> conv2 -> raw out + bn2 partials ----------------
__global__ __launch_bounds__(256) void k_conv2(
    const float* __restrict__ x,
    const float* __restrict__ w1, const float* __restrict__ b1,
    const float* __restrict__ prm1, const float* __restrict__ prelu1,
    const float* __restrict__ w2, const float* __restrict__ b2,
    float* __restrict__ sig, float* __restrict__ part2)
{
  __shared__ float xb[1024];
  __shared__ float h1p[16*136];
  __shared__ float w2s[32*16*12];
  __shared__ float w1s[128];
  __shared__ float p1s[32];
  int tid = threadIdx.x; int b = blockIdx.x;
  *(float4*)&xb[tid*4] = *(const float4*)&x[b*1024 + tid*4];
  for (int i=tid; i<5120; i+=256) { int ff=i/10, k=i-ff*10; w2s[ff*12+k] = w2[i]; }
  if (tid<128) w1s[tid] = w1[tid];
  if (tid<32)  p1s[tid] = prm1[tid];
  float a1 = prelu1[0];
  __syncthreads();
#pragma unroll
  for (int r=0; r<8; ++r) {
    int o = tid + 256*r; int f = o>>7, t = o&127;
    float v = b1[f];
#pragma unroll
    for (int ch=0; ch<8; ++ch) v = fmaf(xb[ch*128+t], w1s[f*8+ch], v);
    v = fmaf(v, p1s[2*f], p1s[2*f+1]);
    v = (v>=0.f) ? v : a1*v;
    h1p[f*136 + t] = v;
  }
  __syncthreads();
  int f2 = tid>>3, wb = (tid&7)*8;
  float acc[8];
  float bb = b2[f2];
#pragma unroll
  for (int j=0;j<8;++j) acc[j]=bb;
  for (int f1=0; f1<16; ++f1) {
    const float* hrow = &h1p[f1*136 + 2*wb];
    float hw[24];
#pragma unroll
    for (int m=0;m<6;++m) *(float4*)&hw[m*4] = *(const float4*)&hrow[m*4];
    const float* wr = &w2s[(f2*16+f1)*12];
    float wk[10];
    *(float4*)&wk[0] = *(const float4*)&wr[0];
    *(float4*)&wk[4] = *(const float4*)&wr[4];
    wk[8]=wr[8]; wk[9]=wr[9];
#pragma unroll
    for (int j=0;j<8;++j)
#pragma unroll
      for (int k=0;k<10;++k) acc[j] = fmaf(hw[2*j+k], wk[k], acc[j]);
  }
  float s=0.f, q=0.f;
#pragma unroll
  for (int j=0;j<8;++j) {
    int w = wb+j;
    if (w < 60) { sig[b*1920 + f2*60 + w] = acc[j]; s += acc[j]; q = fmaf(acc[j],acc[j],q); }
  }
  s += __shfl_down(s,4,8); q += __shfl_down(q,4,8);
  s += __shfl_down(s,2,8); q += __shfl_down(q,2,8);
  s += __shfl_down(s,1,8); q += __shfl_down(q,1,8);
  if ((tid&7)==0) {
    part2[(size_t)b*64 + 2*f2]     = s;
    part2[(size_t)b*64 + 2*f2 + 1] = q;
  }
}

// ---------------- cosine table ----------------
__global__ void k_costab(float* __restrict__ ct)
{
  int i = blockIdx.x*256 + threadIdx.x;
  if (i < 3600) {
    int k = i/60, n = i - k*60;
    int m = (k*n) % 60;
    ct[i] = cosf(0.104719755119659775f * (float)m);
  }
}

// ---------------- bn2-apply + prelu (in-place) + cos transform -> fft ----------------
__global__ __launch_bounds__(256) void k_sigfft(
    float* __restrict__ sig, float* __restrict__ fft,
    const float* __restrict__ prm2, const float* __restrict__ prelu2,
    const float* __restrict__ ctab)
{
  __shared__ float ct[3600];
  __shared__ float rowb[4][4][60];
  int tid = threadIdx.x;
  for (int i=tid; i<3600; i+=256) ct[i] = ctab[i];
  int r4 = tid>>6, lane = tid&63;
  float a2 = prelu2[0];
  __syncthreads();
#pragma unroll
  for (int it=0; it<4; ++it) {
    int row = blockIdx.x*16 + it*4 + r4;
    int c = row & 31;
    float sc = prm2[2*c], sh = prm2[2*c+1];
    size_t base = (size_t)row*60;
    if (lane < 60) {
      float v = fmaf(sig[base+lane], sc, sh);
      v = (v>=0.f) ? v : a2*v;
      rowb[it][r4][lane] = v;
      sig[base+lane] = v;
    }
    if (lane < 60) {
      float s = 0.f;
      const float* rb = rowb[it][r4];
#pragma unroll 6
      for (int n=0; n<60; ++n) s = fmaf(rb[n], ct[n*60+lane], s);
      fft[base+lane] = s;
    }
  }
}

// ---------------- x -> bf16 MFMA B-fragment layout ----------------
// frag[((t*256 + stile)*64 + lane)*8 + j] = X[t][16*stile + (lane&15)][8*(lane>>4)+j]
__global__ __launch_bounds__(256) void k_xfrag(const float* __restrict__ src, short* __restrict__ frag)
{
  __shared__ float XS[64*33];
  const int tid = threadIdx.x;
  const int bid = blockIdx.x;            // t*64 + sblk
  const int t = bid >> 6, sblk = bid & 63;
  const float* sp = src + (size_t)t*131072 + (size_t)sblk*2048;
  {
    float4 v0 = *(const float4*)&sp[tid*8];
    float4 v1 = *(const float4*)&sp[tid*8 + 4];
    int s = tid >> 2, k = (tid & 3) * 8;
    float* d = &XS[s*33 + k];
    d[0]=v0.x; d[1]=v0.y; d[2]=v0.z; d[3]=v0.w;
    d[4]=v1.x; d[5]=v1.y; d[6]=v1.z; d[7]=v1.w;
  }
  __syncthreads();
  const int stile = tid >> 6, l = tid & 63;
  const int m = l & 15, g = l >> 4;
  const float* rp = &XS[(stile*16 + m)*33 + g*8];
  bf16x8 v;
#pragma unroll
  for (int j=0;j<8;++j) v[j] = f2bf(rp[j]);
  *(bf16x8*)(frag + ((size_t)(t*256 + sblk*4 + stile)*64 + l)*8) = v;
}

// ---------------- MFMA bidirectional LSTM, sig+fft cols fused ----------------
// block = 4 waves = (a: unit-group 16, ch: col-half 64); cols = 64 sig + 64 fft samples
// grid (64 sample-blocks, 2 dirs, nbranch)
__global__ __launch_bounds__(256,1) void k_lstm_mfma(
    const short* __restrict__ fragSA, const short* __restrict__ fragFA,
    const short* __restrict__ fragSB, const short* __restrict__ fragFB,
    float* __restrict__ routA, float* __restrict__ routB,
    const float* __restrict__ wihf, const float* __restrict__ whhf,
    const float* __restrict__ bihf, const float* __restrict__ bhhf,
    const float* __restrict__ wihr, const float* __restrict__ whhr,
    const float* __restrict__ bihr, const float* __restrict__ bhhr,
    int zsel)
{
  __shared__ short hbuf[2][5120];        // [buf][col*40 + u] bf16, col 0..127, u 0..31
  const int tid = threadIdx.x;
  const int l = tid & 63, wv = tid >> 6;
  const int a = wv >> 1, ch = wv & 1;
  const int m = l & 15, g = l >> 4;
  const int sb = blockIdx.x * 64;
  const int dir = blockIdx.y;
  const int br = (gridDim.z == 2) ? blockIdx.z : zsel;
  const short* fragS = br ? fragSB : fragSA;
  const short* fragF = br ? fragFB : fragFA;
  float* out = br ? routB : routA;
  const float* wih = dir ? wihr : wihf;
  const float* whh = dir ? whhr : whhf;
  const float* bih = dir ? bihr : bihf;
  const float* bhh = dir ? bhhr : bhhf;

  // A fragments: lane l holds A[row=l&15][k=8*(l>>4)+j] of each 16x32 tile
  bf16x8 Ax[4], Ah[4];
#pragma unroll
  for (int G=0; G<4; ++G) {
    const float* wr = wih + (size_t)(32*G + 16*a + m)*32 + 8*g;
    const float* hr = whh + (size_t)(32*G + 16*a + m)*32 + 8*g;
#pragma unroll
    for (int j=0;j<8;++j){ Ax[G][j]=f2bf(wr[j]); Ah[G][j]=f2bf(hr[j]); }
  }
  float bias[16];
#pragma unroll
  for (int G=0;G<4;++G)
#pragma unroll
    for (int r=0;r<4;++r){
      int row = 32*G + 16*a + 4*g + r;
      bias[G*4+r] = bih[row] + bhh[row];
    }
  for (int i=tid; i<2560; i+=256) ((int*)hbuf[1])[i] = 0;

  const short* fsrc = ch ? fragF : fragS;
  const int st0 = sb >> 4;
  const int tt0 = dir ? 59 : 0;
  bf16x8 bx[4];
#pragma unroll
  for (int ct=0; ct<4; ++ct)
    bx[ct] = *(const bf16x8*)(fsrc + ((size_t)(tt0*256 + st0 + ct)*64 + l)*8);

  float cst[16];
#pragma unroll
  for (int i=0;i<16;++i) cst[i]=0.f;

  __syncthreads();

#pragma unroll 2
  for (int q=0; q<60; ++q) {
    const int tt = dir ? (59-q) : q;
    const short* hrd = hbuf[(q+1)&1];
    bf16x8 bh[4];
#pragma unroll
    for (int ct=0; ct<4; ++ct)
      bh[ct] = *(const bf16x8*)(hrd + (64*ch + 16*ct + m)*40 + 8*g);
    bf16x8 bx2[4];
    if (q < 59) {
      const int tn = dir ? (58-q) : (q+1);
#pragma unroll
      for (int ct=0; ct<4; ++ct)
        bx2[ct] = *(const bf16x8*)(fsrc + ((size_t)(tn*256 + st0 + ct)*64 + l)*8);
    }
    f32x4 acc[16];
#pragma unroll
    for (int G=0; G<4; ++G) {
      f32x4 binit;
      binit[0]=bias[G*4]; binit[1]=bias[G*4+1]; binit[2]=bias[G*4+2]; binit[3]=bias[G*4+3];
#pragma unroll
      for (int ct=0; ct<4; ++ct) {
        f32x4 t0 = __builtin_amdgcn_mfma_f32_16x16x32_bf16(Ax[G], bx[ct], binit, 0,0,0);
        acc[G*4+ct] = __builtin_amdgcn_mfma_f32_16x16x32_bf16(Ah[G], bh[ct], t0, 0,0,0);
      }
    }
    short* hwr = hbuf[q&1];
#pragma unroll
    for (int ct=0; ct<4; ++ct) {
      s16x4 hv;
#pragma unroll
      for (int r=0; r<4; ++r) {
        float gi = acc[0*4+ct][r], gf = acc[1*4+ct][r];
        float gg = acc[2*4+ct][r], go = acc[3*4+ct][r];
        float c = sigf(gf)*cst[ct*4+r] + sigf(gi)*tanhfast(gg);
        cst[ct*4+r] = c;
        hv[r] = f2bf(sigf(go)*tanhfast(c));
      }
      *(s16x4*)(hwr + (64*ch + 16*ct + m)*40 + 16*a + 4*g) = hv;
    }
    __syncthreads();
    // out = h_sig + h_fft, coalesced-ish float4 writes
#pragma unroll
    for (int i2=0; i2<2; ++i2) {
      int s = 32*ch + 16*i2 + m;
      const s16x4 h1 = *(const s16x4*)(hwr + s*40 + 16*a + 4*g);
      const s16x4 h2 = *(const s16x4*)(hwr + (64+s)*40 + 16*a + 4*g);
      float4 o;
      o.x = bf2f(h1[0])+bf2f(h2[0]);
      o.y = bf2f(h1[1])+bf2f(h2[1]);
      o.z = bf2f(h1[2])+bf2f(h2[2]);
      o.w = bf2f(h1[3])+bf2f(h2[3]);
      *(float4*)(out + (size_t)tt*262144 + (size_t)(sb+s)*64 + dir*32 + 16*a + 4*g) = o;
    }
#pragma unroll
    for (int ct=0; ct<4; ++ct) bx[ct] = bx2[ct];
  }
}

// ---------------- bnf stats ----------------
__global__ __launch_bounds__(256) void k_bnfstats(const float* __restrict__ rb, float* __restrict__ acc)
{
  int col = blockIdx.x*256 + threadIdx.x;
  size_t r0 = (size_t)blockIdx.y*256;
  const float* p = rb + r0*3840 + col;
  float s=0.f, q=0.f;
  for (int r=0; r<256; ++r) { float v = p[(size_t)r*3840]; s += v; q = fmaf(v,v,q); }
  atomicAdd(&acc[2*col], s); atomicAdd(&acc[2*col+1], q);
}

// ---------------- finalize ----------------
__global__ void k_finalize_bn(const float* __restrict__ acc, const float* __restrict__ g,
                              const float* __restrict__ b, float* __restrict__ prm,
                              int C, float invN)
{
  int i = blockIdx.x*blockDim.x + threadIdx.x;
  if (i < C) {
    float m = acc[2*i]*invN;
    float v = acc[2*i+1]*invN - m*m;
    float sc = g[i] / sqrtf(v + EPS);
    prm[2*i]   = sc;
    prm[2*i+1] = fmaf(-m, sc, b[i]);
  }
}

// ---------------- bn1d-apply + correlation + final conv ----------------
__global__ __launch_bounds__(64) void k_corr(
    const float* __restrict__ ra, const float* __restrict__ rb,
    const float* __restrict__ pfa, const float* __restrict__ pfb,
    const float* __restrict__ cw, const float* __restrict__ cb,
    float* __restrict__ dout)
{
  __shared__ float sxt[12], sxx[12], stt[12], cv[12];
  int lane = threadIdx.x; int r = blockIdx.x;
  if (lane < 12) { sxt[lane]=0.f; sxx[lane]=0.f; stt[lane]=0.f; }
  __syncthreads();
  const float* pa = ra + (size_t)r*3840;
  const float* pb = rb + (size_t)r*3840;
  float xt0=0,xx0=0,tt0=0, xt1=0,xx1=0,tt1=0, xt2=0,xx2=0,tt2=0;
  for (int i=0; i<60; i+=3) {
    { int fe = lane + 64*i;
      float a = fmaf(pa[fe], pfa[2*fe], pfa[2*fe+1]);
      float b = fmaf(pb[fe], pfb[2*fe], pfb[2*fe+1]);
      xt0 = fmaf(a,b,xt0); xx0 = fmaf(a,a,xx0); tt0 = fmaf(b,b,tt0); }
    { int fe = lane + 64*(i+1);
      float a = fmaf(pa[fe], pfa[2*fe], pfa[2*fe+1]);
      float b = fmaf(pb[fe], pfb[2*fe], pfb[2*fe+1]);
      xt1 = fmaf(a,b,xt1); xx1 = fmaf(a,a,xx1); tt1 = fmaf(b,b,tt1); }
    { int fe = lane + 64*(i+2);
      float a = fmaf(pa[fe], pfa[2*fe], pfa[2*fe+1]);
      float b = fmaf(pb[fe], pfb[2*fe], pfb[2*fe+1]);
      xt2 = fmaf(a,b,xt2); xx2 = fmaf(a,a,xx2); tt2 = fmaf(b,b,tt2); }
  }
  int c0 = lane % 12;
  int c1 = (c0+4) % 12;
  int c2 = (c0+8) % 12;
  atomicAdd(&sxt[c0], xt0); atomicAdd(&sxx[c0], xx0); atomicAdd(&stt[c0], tt0);
  atomicAdd(&sxt[c1], xt1); atomicAdd(&sxx[c1], xx1); atomicAdd(&stt[c1], tt1);
  atomicAdd(&sxt[c2], xt2); atomicAdd(&sxx[c2], xx2); atomicAdd(&stt[c2], tt2);
  __syncthreads();
  if (lane < 12) {
    float corr = sxt[lane] / sqrtf(stt[lane]) / sqrtf(sxx[lane]);
    cv[lane] = corr;
    dout[49152 + r*12 + lane] = corr;
  }
  __syncthreads();
  if (lane < 12) {
    float o = cb[0];
#pragma unroll
    for (int k=0; k<5; ++k) { int j = lane + k - 2; if (j>=0 && j<12) o = fmaf(cv[j], cw[k], o); }
    dout[r*12 + lane] = o;
  }
}

// ---------------- host ----------------
extern "C" void kernel_launch(void* const* d_in, const int* in_sizes, int n_in,
                              void* d_out, int out_size, void* d_ws, size_t ws_size,
                              hipStream_t stream)
{
  const float* x    = (const float*)d_in[0];
  const float* tpl  = (const float*)d_in[1];
  const float* w1   = (const float*)d_in[2];
  const float* b1   = (const float*)d_in[3];
  const float* g1   = (const float*)d_in[4];
  const float* bb1  = (const float*)d_in[5];
  const float* p1   = (const float*)d_in[6];
  const float* w2   = (const float*)d_in[7];
  const float* b2   = (const float*)d_in[8];
  const float* g2   = (const float*)d_in[9];
  const float* bb2  = (const float*)d_in[10];
  const float* p2   = (const float*)d_in[11];
  const float* wihf = (const float*)d_in[12];
  const float* whhf = (const float*)d_in[13];
  const float* bihf = (const float*)d_in[14];
  const float* bhhf = (const float*)d_in[15];
  const float* wihr = (const float*)d_in[16];
  const float* whhr = (const float*)d_in[17];
  const float* bihr = (const float*)d_in[18];
  const float* bhhr = (const float*)d_in[19];
  const float* gf   = (const float*)d_in[20];
  const float* bf   = (const float*)d_in[21];
  const float* cw   = (const float*)d_in[22];
  const float* cb   = (const float*)d_in[23];
  float* W   = (float*)d_ws;
  float* out = (float*)d_out;

  constexpr size_t PRM1A=64, PRM1B=96, PRM2A=256, PRM2B=320;
  constexpr size_t ACCFA=512, ACCFB=8192, PRMFA=15872, PRMFB=23552, CTAB=31232;
  constexpr size_t P1P=35072, P2P=43264;
  constexpr size_t SIGSZ = 7864320, RSZ = 15728640, FRAGF = 3932160; // frag size in floats
  constexpr size_t BIG0 = 307200;
  // tier1: sigA|fftA|sigB|fftB|rbufA|rbufB|fragSA|fragFA|fragSB|fragFB
  constexpr size_t F_SIGA=BIG0, F_FFTA=F_SIGA+SIGSZ, F_SIGB=F_FFTA+SIGSZ, F_FFTB=F_SIGB+SIGSZ;
  constexpr size_t F_RBUFA=F_FFTB+SIGSZ, F_RBUFB=F_RBUFA+RSZ;
  constexpr size_t F_FR0=F_RBUFB+RSZ;
  constexpr size_t F_TOTAL=(F_FR0 + 4*FRAGF)*sizeof(float);
  // tier2: sig|fft|rbufA|rbufB|fragS|fragF  (per-branch reuse)
  constexpr size_t T_SIG=BIG0, T_FFT=T_SIG+SIGSZ, T_RBUFA=T_FFT+SIGSZ, T_RBUFB=T_RBUFA+RSZ;
  constexpr size_t T_FR0=T_RBUFB+RSZ;

  const bool fast = ws_size >= F_TOTAL;

  hipMemsetAsync(W, 0, 65536*sizeof(float)/sizeof(float)>0?262144:262144, stream); // 256KB covers smalls
  k_costab<<<15,256,0,stream>>>(W+CTAB);

  if (fast) {
    for (int br=0; br<2; ++br) {
      const float* xin  = br ? tpl : x;
      float* prm1 = W + (br ? PRM1B : PRM1A);
      float* prm2 = W + (br ? PRM2B : PRM2A);
      float* sig  = W + (br ? F_SIGB : F_SIGA);
      float* fft  = W + (br ? F_FFTB : F_FFTA);
      k_conv1_stats<<<256,256,0,stream>>>(xin, w1, b1, W+P1P);
      k_reduce_finalize<<<16,256,0,stream>>>(W+P1P, 256, 16, g1, bb1, prm1, 1.f/524288.f);
      k_conv2<<<4096,256,0,stream>>>(xin, w1, b1, prm1, p1, w2, b2, sig, W+P2P);
      k_reduce_finalize<<<32,256,0,stream>>>(W+P2P, 4096, 32, g2, bb2, prm2, 1.f/245760.f);
      k_sigfft<<<8192,256,0,stream>>>(sig, fft, prm2, p2, W+CTAB);
    }
    short* frSA = (short*)(W + F_FR0);
    short* frFA = (short*)(W + F_FR0 + FRAGF);
    short* frSB = (short*)(W + F_FR0 + 2*FRAGF);
    short* frFB = (short*)(W + F_FR0 + 3*FRAGF);
    k_xfrag<<<3840,256,0,stream>>>(W+F_SIGA, frSA);
    k_xfrag<<<3840,256,0,stream>>>(W+F_FFTA, frFA);
    k_xfrag<<<3840,256,0,stream>>>(W+F_SIGB, frSB);
    k_xfrag<<<3840,256,0,stream>>>(W+F_FFTB, frFB);
    k_lstm_mfma<<<dim3(64,2,2),256,0,stream>>>(frSA, frFA, frSB, frFB,
        W+F_RBUFA, W+F_RBUFB,
        wihf,whhf,bihf,bhhf, wihr,whhr,bihr,bhhr, 0);
    k_bnfstats<<<dim3(15,16),256,0,stream>>>(W+F_RBUFA, W+ACCFA);
    k_bnfstats<<<dim3(15,16),256,0,stream>>>(W+F_RBUFB, W+ACCFB);
    k_finalize_bn<<<15,256,0,stream>>>(W+ACCFA, gf, bf, W+PRMFA, 3840, 1.f/4096.f);
    k_finalize_bn<<<15,256,0,stream>>>(W+ACCFB, gf, bf, W+PRMFB, 3840, 1.f/4096.f);
    k_corr<<<4096,64,0,stream>>>(W+F_RBUFA, W+F_RBUFB, W+PRMFA, W+PRMFB, cw, cb, out);
  } else {
    short* frS = (short*)(W + T_FR0);
    short* frF = (short*)(W + T_FR0 + FRAGF);
    for (int br=0; br<2; ++br) {
      const float* xin  = br ? tpl : x;
      float* prm1 = W + (br ? PRM1B : PRM1A);
      float* prm2 = W + (br ? PRM2B : PRM2A);
      float* sig  = W + T_SIG;
      float* fft  = W + T_FFT;
      float* rbuf = W + (br ? T_RBUFB : T_RBUFA);
      k_conv1_stats<<<256,256,0,stream>>>(xin, w1, b1, W+P1P);
      k_reduce_finalize<<<16,256,0,stream>>>(W+P1P, 256, 16, g1, bb1, prm1, 1.f/524288.f);
      k_conv2<<<4096,256,0,stream>>>(xin, w1, b1, prm1, p1, w2, b2, sig, W+P2P);
      k_reduce_finalize<<<32,256,0,stream>>>(W+P2P, 4096, 32, g2, bb2, prm2, 1.f/245760.f);
      k_sigfft<<<8192,256,0,stream>>>(sig, fft, prm2, p2, W+CTAB);
      k_xfrag<<<3840,256,0,stream>>>(sig, frS);
      k_xfrag<<<3840,256,0,stream>>>(fft, frF);
      k_lstm_mfma<<<dim3(64,2,1),256,0,stream>>>(frS, frF, frS, frF,
          rbuf, rbuf, wihf,whhf,bihf,bhhf, wihr,whhr,bihr,bhhr, 0);
    }
    k_bnfstats<<<dim3(15,16),256,0,stream>>>(W+T_RBUFA, W+ACCFA);
    k_bnfstats<<<dim3(15,16),256,0,stream>>>(W+T_RBUFB, W+ACCFB);
    k_finalize_bn<<<15,256,0,stream>>>(W+ACCFA, gf, bf, W+PRMFA, 3840, 1.f/4096.f);
    k_finalize_bn<<<15,256,0,stream>>>(W+ACCFB, gf, bf, W+PRMFB, 3840, 1.f/4096.f);
    k_corr<<<4096,64,0,stream>>>(W+T_RBUFA, W+T_RBUFB, W+PRMFA, W+PRMFB, cw, cb, out);
  }
}

// Round 9
// 652.814 us; speedup vs baseline: 10.3166x; 1.0546x over previous
//
#include <hip/hip_runtime.h>
#include <math.h>

#define EPS 1e-5f

typedef __attribute__((ext_vector_type(8))) short bf16x8;
typedef __attribute__((ext_vector_type(4))) float f32x4;
typedef __attribute__((ext_vector_type(4))) short s16x4;

__device__ __forceinline__ float fast_rcp(float x){ return __builtin_amdgcn_rcpf(x); }
__device__ __forceinline__ float sigf(float x){ return fast_rcp(1.0f + __expf(-x)); }
__device__ __forceinline__ float tanhfast(float x){ return fmaf(2.0f, fast_rcp(1.0f + __expf(-2.0f*x)), -1.0f); }
__device__ __forceinline__ short f2bf(float f){
  unsigned u = __float_as_uint(f);
  u = (u + 0x7FFFu + ((u>>16)&1u)) >> 16;
  return (short)u;
}
__device__ __forceinline__ float bf2f(short s){
  return __uint_as_float(((unsigned)(unsigned short)s) << 16);
}

// ---------------- conv1 + bn1 partial stats ----------------
__global__ __launch_bounds__(256) void k_conv1_stats(
    const float* __restrict__ x, const float* __restrict__ w1,
    const float* __restrict__ b1, float* __restrict__ part)
{
  __shared__ float red[4][32];
  float s[16], q[16];
#pragma unroll
  for (int f=0; f<16; ++f) { s[f]=0.f; q[f]=0.f; }
  float w1r[128];
#pragma unroll
  for (int i=0; i<128; ++i) w1r[i] = w1[i];
  float b1r[16];
#pragma unroll
  for (int f=0; f<16; ++f) b1r[f] = b1[f];
  const int tid = threadIdx.x;
  for (int iter=0; iter<8; ++iter) {
    int n = blockIdx.x*2048 + iter*256 + tid;
    int b = n >> 7, t = n & 127;
    const float* xb = x + b*1024 + t;
    float xv[8];
#pragma unroll
    for (int ch=0; ch<8; ++ch) xv[ch] = xb[ch*128];
#pragma unroll
    for (int f=0; f<16; ++f) {
      float v = b1r[f];
#pragma unroll
      for (int ch=0; ch<8; ++ch) v = fmaf(xv[ch], w1r[f*8+ch], v);
      s[f] += v; q[f] = fmaf(v,v,q[f]);
    }
  }
#pragma unroll
  for (int f=0; f<16; ++f) {
#pragma unroll
    for (int d=32; d>0; d>>=1) { s[f] += __shfl_down(s[f],d); q[f] += __shfl_down(q[f],d); }
  }
  const int lane = tid & 63, wv = tid >> 6;
  if (lane == 0) {
#pragma unroll
    for (int f=0; f<16; ++f) { red[wv][2*f] = s[f]; red[wv][2*f+1] = q[f]; }
  }
  __syncthreads();
  if (tid < 32) {
    float v = red[0][tid] + red[1][tid] + red[2][tid] + red[3][tid];
    part[blockIdx.x*32 + tid] = v;
  }
}

// ---------------- reduce partials + finalize scale/shift ----------------
__global__ __launch_bounds__(256) void k_reduce_finalize(
    const float* __restrict__ part, int nblk, int C,
    const float* __restrict__ g, const float* __restrict__ b,
    float* __restrict__ prm, float invN)
{
  __shared__ float red[4][2];
  const int c = blockIdx.x;
  const int tid = threadIdx.x;
  float s=0.f, q=0.f;
  for (int i=tid; i<nblk; i+=256) {
    s += part[(size_t)i*2*C + 2*c];
    q += part[(size_t)i*2*C + 2*c + 1];
  }
#pragma unroll
  for (int d=32; d>0; d>>=1) { s += __shfl_down(s,d); q += __shfl_down(q,d); }
  const int lane = tid & 63, wv = tid >> 6;
  if (lane==0) { red[wv][0]=s; red[wv][1]=q; }
  __syncthreads();
  if (tid==0) {
    s = red[0][0]+red[1][0]+red[2][0]+red[3][0];
    q = red[0][1]+red[1][1]+red[2][1]+red[3][1];
    float m = s*invN;
    float v = q*invN - m*m;
    float sc = g[c] / sqrtf(v + EPS);
    prm[2*c]   = sc;
    prm[2*c+1] = fmaf(-m, sc, b[c]);
  }
}

// ---------------- conv1(recompute)+bn1+prelu -> conv2 -> raw out + bn2 partials ----------------
__global__ __launch_bounds__(256) void k_conv2(
    const float* __restrict__ x,
    const float* __restrict__ w1, const float* __restrict__ b1,
    const float* __restrict__ prm1, const float* __restrict__ prelu1,
    const float* __restrict__ w2, const float* __restrict__ b2,
    float* __restrict__ sig, float* __restrict__ part2)
{
  __shared__ float xb[1024];
  __shared__ float h1p[16*136];
  __shared__ float w2s[32*16*12];
  __shared__ float w1s[128];
  __shared__ float p1s[32];
  int tid = threadIdx.x; int b = blockIdx.x;
  *(float4*)&xb[tid*4] = *(const float4*)&x[b*1024 + tid*4];
  for (int i=tid; i<5120; i+=256) { int ff=i/10, k=i-ff*10; w2s[ff*12+k] = w2[i]; }
  if (tid<128) w1s[tid] = w1[tid];
  if (tid<32)  p1s[tid] = prm1[tid];
  float a1 = prelu1[0];
  __syncthreads();
#pragma unroll
  for (int r=0; r<8; ++r) {
    int o = tid + 256*r; int f = o>>7, t = o&127;
    float v = b1[f];
#pragma unroll
    for (int ch=0; ch<8; ++ch) v = fmaf(xb[ch*128+t], w1s[f*8+ch], v);
    v = fmaf(v, p1s[2*f], p1s[2*f+1]);
    v = (v>=0.f) ? v : a1*v;
    h1p[f*136 + t] = v;
  }
  __syncthreads();
  int f2 = tid>>3, wb = (tid&7)*8;
  float acc[8];
  float bb = b2[f2];
#pragma unroll
  for (int j=0;j<8;++j) acc[j]=bb;
  for (int f1=0; f1<16; ++f1) {
    const float* hrow = &h1p[f1*136 + 2*wb];
    float hw[24];
#pragma unroll
    for (int m=0;m<6;++m) *(float4*)&hw[m*4] = *(const float4*)&hrow[m*4];
    const float* wr = &w2s[(f2*16+f1)*12];
    float wk[10];
    *(float4*)&wk[0] = *(const float4*)&wr[0];
    *(float4*)&wk[4] = *(const float4*)&wr[4];
    wk[8]=wr[8]; wk[9]=wr[9];
#pragma unroll
    for (int j=0;j<8;++j)
#pragma unroll
      for (int k=0;k<10;++k) acc[j] = fmaf(hw[2*j+k], wk[k], acc[j]);
  }
  float s=0.f, q=0.f;
#pragma unroll
  for (int j=0;j<8;++j) {
    int w = wb+j;
    if (w < 60) { sig[b*1920 + f2*60 + w] = acc[j]; s += acc[j]; q = fmaf(acc[j],acc[j],q); }
  }
  s += __shfl_down(s,4,8); q += __shfl_down(q,4,8);
  s += __shfl_down(s,2,8); q += __shfl_down(q,2,8);
  s += __shfl_down(s,1,8); q += __shfl_down(q,1,8);
  if ((tid&7)==0) {
    part2[(size_t)b*64 + 2*f2]     = s;
    part2[(size_t)b*64 + 2*f2 + 1] = q;
  }
}

// ---------------- cosine table ----------------
__global__ void k_costab(float* __restrict__ ct)
{
  int i = blockIdx.x*256 + threadIdx.x;
  if (i < 3600) {
    int k = i/60, n = i - k*60;
    int m = (k*n) % 60;
    ct[i] = cosf(0.104719755119659775f * (float)m);
  }
}

// ---------------- bn2-apply + prelu (in-place) + cos transform -> fft ----------------
__global__ __launch_bounds__(256) void k_sigfft(
    float* __restrict__ sig, float* __restrict__ fft,
    const float* __restrict__ prm2, const float* __restrict__ prelu2,
    const float* __restrict__ ctab)
{
  __shared__ float ct[3600];
  __shared__ float rowb[4][4][60];
  int tid = threadIdx.x;
  for (int i=tid; i<3600; i+=256) ct[i] = ctab[i];
  int r4 = tid>>6, lane = tid&63;
  float a2 = prelu2[0];
  __syncthreads();
#pragma unroll
  for (int it=0; it<4; ++it) {
    int row = blockIdx.x*16 + it*4 + r4;
    int c = row & 31;
    float sc = prm2[2*c], sh = prm2[2*c+1];
    size_t base = (size_t)row*60;
    if (lane < 60) {
      float v = fmaf(sig[base+lane], sc, sh);
      v = (v>=0.f) ? v : a2*v;
      rowb[it][r4][lane] = v;
      sig[base+lane] = v;
    }
    if (lane < 60) {
      float s = 0.f;
      const float* rb = rowb[it][r4];
#pragma unroll 6
      for (int n=0; n<60; ++n) s = fmaf(rb[n], ct[n*60+lane], s);
      fft[base+lane] = s;
    }
  }
}

// ---------------- sig+fft -> combined bf16 MFMA B-fragment ----------------
// frag[((t*512+sg)*64 + l)*8 + j]:
//   m=l&15, g=l>>4; stream = (m<8 ? sig : fft); sample = 8*sg + (m&7); k = 8g+j
__global__ __launch_bounds__(256) void k_xfrag2(
    const float* __restrict__ sig, const float* __restrict__ fft,
    short* __restrict__ frag)
{
  const int tid = threadIdx.x;
  const int wv = tid >> 6, l = tid & 63;
  const int id = blockIdx.x*4 + wv;          // t*512 + sg
  const int t = id >> 9, sg = id & 511;
  const int m = l & 15, g = l >> 4;
  const float* src = (m < 8) ? sig : fft;
  const float* p = src + (size_t)t*131072 + (size_t)(8*sg + (m&7))*32 + 8*g;
  float4 v0 = *(const float4*)p;
  float4 v1 = *(const float4*)(p+4);
  bf16x8 v;
  v[0]=f2bf(v0.x); v[1]=f2bf(v0.y); v[2]=f2bf(v0.z); v[3]=f2bf(v0.w);
  v[4]=f2bf(v1.x); v[5]=f2bf(v1.y); v[6]=f2bf(v1.z); v[7]=f2bf(v1.w);
  *(bf16x8*)(frag + ((size_t)id*64 + l)*8) = v;
}

// ---------------- barrier-free MFMA LSTM: wave = 8 samples x {sig,fft} ----------------
// 128 gate rows x 16 cols per wave; h-feedback wave-private in LDS; r1+r2 via shfl_xor(8)
__global__ __launch_bounds__(64,2) void k_lstm8(
    const short* __restrict__ fragA, const short* __restrict__ fragB,
    float* __restrict__ routA, float* __restrict__ routB,
    const float* __restrict__ wihf, const float* __restrict__ whhf,
    const float* __restrict__ bihf, const float* __restrict__ bhhf,
    const float* __restrict__ wihr, const float* __restrict__ whhr,
    const float* __restrict__ bihr, const float* __restrict__ bhhr)
{
  __shared__ short hb[640];                  // [col m][u] stride 40 halves
  const int l = threadIdx.x & 63;
  const int m = l & 15, g = l >> 4;
  const int sg = blockIdx.x;                 // 0..511
  const int dir = blockIdx.y;
  const int br = blockIdx.z;
  const short* frag = br ? fragB : fragA;
  float* out = br ? routB : routA;
  const float* wih = dir ? wihr : wihf;
  const float* whh = dir ? whhr : whhf;
  const float* bih = dir ? bihr : bihf;
  const float* bhh = dir ? bhhr : bhhf;

  // A fragments: tile rt rows 16rt..16rt+15; lane holds A[m][8g+j]
  bf16x8 Ax[8], Ah[8];
#pragma unroll
  for (int rt=0; rt<8; ++rt) {
    const float* wr = wih + (size_t)(16*rt+m)*32 + 8*g;
    const float* hr = whh + (size_t)(16*rt+m)*32 + 8*g;
#pragma unroll
    for (int j=0;j<8;++j){ Ax[rt][j]=f2bf(wr[j]); Ah[rt][j]=f2bf(hr[j]); }
  }
  // C-init biases: C row = 16rt + 4g + r
  f32x4 bias[8];
#pragma unroll
  for (int rt=0; rt<8; ++rt)
#pragma unroll
    for (int r=0;r<4;++r){ int R=16*rt+4*g+r; bias[rt][r]=bih[R]+bhh[R]; }

  for (int i=l; i<320; i+=64) ((int*)hb)[i] = 0;

  float cst[2][4];
#pragma unroll
  for (int h2=0;h2<2;++h2)
#pragma unroll
    for (int r=0;r<4;++r) cst[h2][r]=0.f;

  const int tt0 = dir ? 59 : 0;
  bf16x8 bx = *(const bf16x8*)(frag + ((size_t)(tt0*512+sg)*64 + l)*8);

  for (int q=0; q<60; ++q) {
    const int tt = dir ? (59-q) : q;
    bf16x8 bh = *(const bf16x8*)(hb + m*40 + 8*g);
    bf16x8 bxn;
    if (q < 59) {
      const int tn = dir ? (58-q) : (q+1);
      bxn = *(const bf16x8*)(frag + ((size_t)(tn*512+sg)*64 + l)*8);
    }
    f32x4 acc[8];
#pragma unroll
    for (int rt=0; rt<8; ++rt) {
      acc[rt] = __builtin_amdgcn_mfma_f32_16x16x32_bf16(Ax[rt], bx, bias[rt], 0,0,0);
      acc[rt] = __builtin_amdgcn_mfma_f32_16x16x32_bf16(Ah[rt], bh, acc[rt], 0,0,0);
    }
    // gates: unit u = 16h2+4g+r, gate G at acc[2G+h2][r]
#pragma unroll
    for (int h2=0; h2<2; ++h2) {
      s16x4 hv;
      float hnf[4];
#pragma unroll
      for (int r=0; r<4; ++r) {
        float gi = acc[h2][r],   gf = acc[2+h2][r];
        float gg = acc[4+h2][r], go = acc[6+h2][r];
        float cn = sigf(gf)*cst[h2][r] + sigf(gi)*tanhfast(gg);
        cst[h2][r] = cn;
        float hn = sigf(go)*tanhfast(cn);
        hnf[r] = hn; hv[r] = f2bf(hn);
      }
      *(s16x4*)(hb + m*40 + 16*h2 + 4*g) = hv;
      float4 o;
      o.x = hnf[0] + __shfl_xor(hnf[0], 8);
      o.y = hnf[1] + __shfl_xor(hnf[1], 8);
      o.z = hnf[2] + __shfl_xor(hnf[2], 8);
      o.w = hnf[3] + __shfl_xor(hnf[3], 8);
      if (m < 8)
        *(float4*)(out + (size_t)tt*262144 + (size_t)(8*sg+m)*64 + dir*32 + 16*h2 + 4*g) = o;
    }
    bx = bxn;
  }
}

// ---------------- bnf stats ----------------
__global__ __launch_bounds__(256) void k_bnfstats(const float* __restrict__ rb, float* __restrict__ acc)
{
  int col = blockIdx.x*256 + threadIdx.x;
  size_t r0 = (size_t)blockIdx.y*256;
  const float* p = rb + r0*3840 + col;
  float s=0.f, q=0.f;
  for (int r=0; r<256; ++r) { float v = p[(size_t)r*3840]; s += v; q = fmaf(v,v,q); }
  atomicAdd(&acc[2*col], s); atomicAdd(&acc[2*col+1], q);
}

// ---------------- finalize ----------------
__global__ void k_finalize_bn(const float* __restrict__ acc, const float* __restrict__ g,
                              const float* __restrict__ b, float* __restrict__ prm,
                              int C, float invN)
{
  int i = blockIdx.x*blockDim.x + threadIdx.x;
  if (i < C) {
    float m = acc[2*i]*invN;
    float v = acc[2*i+1]*invN - m*m;
    float sc = g[i] / sqrtf(v + EPS);
    prm[2*i]   = sc;
    prm[2*i+1] = fmaf(-m, sc, b[i]);
  }
}

// ---------------- bn1d-apply + correlation + final conv ----------------
__global__ __launch_bounds__(64) void k_corr(
    const float* __restrict__ ra, const float* __restrict__ rb,
    const float* __restrict__ pfa, const float* __restrict__ pfb,
    const float* __restrict__ cw, const float* __restrict__ cb,
    float* __restrict__ dout)
{
  __shared__ float sxt[12], sxx[12], stt[12], cv[12];
  int lane = threadIdx.x; int r = blockIdx.x;
  if (lane < 12) { sxt[lane]=0.f; sxx[lane]=0.f; stt[lane]=0.f; }
  __syncthreads();
  const float* pa = ra + (size_t)r*3840;
  const float* pb = rb + (size_t)r*3840;
  float xt0=0,xx0=0,tt0=0, xt1=0,xx1=0,tt1=0, xt2=0,xx2=0,tt2=0;
  for (int i=0; i<60; i+=3) {
    { int fe = lane + 64*i;
      float a = fmaf(pa[fe], pfa[2*fe], pfa[2*fe+1]);
      float b = fmaf(pb[fe], pfb[2*fe], pfb[2*fe+1]);
      xt0 = fmaf(a,b,xt0); xx0 = fmaf(a,a,xx0); tt0 = fmaf(b,b,tt0); }
    { int fe = lane + 64*(i+1);
      float a = fmaf(pa[fe], pfa[2*fe], pfa[2*fe+1]);
      float b = fmaf(pb[fe], pfb[2*fe], pfb[2*fe+1]);
      xt1 = fmaf(a,b,xt1); xx1 = fmaf(a,a,xx1); tt1 = fmaf(b,b,tt1); }
    { int fe = lane + 64*(i+2);
      float a = fmaf(pa[fe], pfa[2*fe], pfa[2*fe+1]);
      float b = fmaf(pb[fe], pfb[2*fe], pfb[2*fe+1]);
      xt2 = fmaf(a,b,xt2); xx2 = fmaf(a,a,xx2); tt2 = fmaf(b,b,tt2); }
  }
  int c0 = lane % 12;
  int c1 = (c0+4) % 12;
  int c2 = (c0+8) % 12;
  atomicAdd(&sxt[c0], xt0); atomicAdd(&sxx[c0], xx0); atomicAdd(&stt[c0], tt0);
  atomicAdd(&sxt[c1], xt1); atomicAdd(&sxx[c1], xx1); atomicAdd(&stt[c1], tt1);
  atomicAdd(&sxt[c2], xt2); atomicAdd(&sxx[c2], xx2); atomicAdd(&stt[c2], tt2);
  __syncthreads();
  if (lane < 12) {
    float corr = sxt[lane] / sqrtf(stt[lane]) / sqrtf(sxx[lane]);
    cv[lane] = corr;
    dout[49152 + r*12 + lane] = corr;
  }
  __syncthreads();
  if (lane < 12) {
    float o = cb[0];
#pragma unroll
    for (int k=0; k<5; ++k) { int j = lane + k - 2; if (j>=0 && j<12) o = fmaf(cv[j], cw[k], o); }
    dout[r*12 + lane] = o;
  }
}

// ---------------- host ----------------
extern "C" void kernel_launch(void* const* d_in, const int* in_sizes, int n_in,
                              void* d_out, int out_size, void* d_ws, size_t ws_size,
                              hipStream_t stream)
{
  const float* x    = (const float*)d_in[0];
  const float* tpl  = (const float*)d_in[1];
  const float* w1   = (const float*)d_in[2];
  const float* b1   = (const float*)d_in[3];
  const float* g1   = (const float*)d_in[4];
  const float* bb1  = (const float*)d_in[5];
  const float* p1   = (const float*)d_in[6];
  const float* w2   = (const float*)d_in[7];
  const float* b2   = (const float*)d_in[8];
  const float* g2   = (const float*)d_in[9];
  const float* bb2  = (const float*)d_in[10];
  const float* p2   = (const float*)d_in[11];
  const float* wihf = (const float*)d_in[12];
  const float* whhf = (const float*)d_in[13];
  const float* bihf = (const float*)d_in[14];
  const float* bhhf = (const float*)d_in[15];
  const float* wihr = (const float*)d_in[16];
  const float* whhr = (const float*)d_in[17];
  const float* bihr = (const float*)d_in[18];
  const float* bhhr = (const float*)d_in[19];
  const float* gf   = (const float*)d_in[20];
  const float* bf   = (const float*)d_in[21];
  const float* cw   = (const float*)d_in[22];
  const float* cb   = (const float*)d_in[23];
  float* W   = (float*)d_ws;
  float* out = (float*)d_out;

  constexpr size_t PRM1A=64, PRM1B=96, PRM2A=256, PRM2B=320;
  constexpr size_t ACCFA=512, ACCFB=8192, PRMFA=15872, PRMFB=23552, CTAB=31232;
  constexpr size_t P1P=35072, P2P=43264;
  constexpr size_t SIGSZ = 7864320, RSZ = 15728640, FRAGF = 7864320; // frag floats per branch
  constexpr size_t BIG0 = 307200;
  // fast: sigA|fftA|sigB|fftB|rbufA|rbufB|fragA|fragB
  constexpr size_t F_SIGA=BIG0, F_FFTA=F_SIGA+SIGSZ, F_SIGB=F_FFTA+SIGSZ, F_FFTB=F_SIGB+SIGSZ;
  constexpr size_t F_RBUFA=F_FFTB+SIGSZ, F_RBUFB=F_RBUFA+RSZ;
  constexpr size_t F_FR0=F_RBUFB+RSZ;
  constexpr size_t F_TOTAL=(F_FR0 + 2*FRAGF)*sizeof(float);
  // slow: sig|fft|rbufA|rbufB|frag
  constexpr size_t T_SIG=BIG0, T_FFT=T_SIG+SIGSZ, T_RBUFA=T_FFT+SIGSZ, T_RBUFB=T_RBUFA+RSZ;
  constexpr size_t T_FR0=T_RBUFB+RSZ;

  const bool fast = ws_size >= F_TOTAL;

  hipMemsetAsync(W, 0, 262144, stream);      // zero small scratch (stat accumulators)
  k_costab<<<15,256,0,stream>>>(W+CTAB);

  if (fast) {
    for (int br=0; br<2; ++br) {
      const float* xin  = br ? tpl : x;
      float* prm1 = W + (br ? PRM1B : PRM1A);
      float* prm2 = W + (br ? PRM2B : PRM2A);
      float* sig  = W + (br ? F_SIGB : F_SIGA);
      float* fft  = W + (br ? F_FFTB : F_FFTA);
      k_conv1_stats<<<256,256,0,stream>>>(xin, w1, b1, W+P1P);
      k_reduce_finalize<<<16,256,0,stream>>>(W+P1P, 256, 16, g1, bb1, prm1, 1.f/524288.f);
      k_conv2<<<4096,256,0,stream>>>(xin, w1, b1, prm1, p1, w2, b2, sig, W+P2P);
      k_reduce_finalize<<<32,256,0,stream>>>(W+P2P, 4096, 32, g2, bb2, prm2, 1.f/245760.f);
      k_sigfft<<<8192,256,0,stream>>>(sig, fft, prm2, p2, W+CTAB);
    }
    short* frA = (short*)(W + F_FR0);
    short* frB = (short*)(W + F_FR0 + FRAGF);
    k_xfrag2<<<7680,256,0,stream>>>(W+F_SIGA, W+F_FFTA, frA);
    k_xfrag2<<<7680,256,0,stream>>>(W+F_SIGB, W+F_FFTB, frB);
    k_lstm8<<<dim3(512,2,2),64,0,stream>>>(frA, frB, W+F_RBUFA, W+F_RBUFB,
        wihf,whhf,bihf,bhhf, wihr,whhr,bihr,bhhr);
    k_bnfstats<<<dim3(15,16),256,0,stream>>>(W+F_RBUFA, W+ACCFA);
    k_bnfstats<<<dim3(15,16),256,0,stream>>>(W+F_RBUFB, W+ACCFB);
    k_finalize_bn<<<15,256,0,stream>>>(W+ACCFA, gf, bf, W+PRMFA, 3840, 1.f/4096.f);
    k_finalize_bn<<<15,256,0,stream>>>(W+ACCFB, gf, bf, W+PRMFB, 3840, 1.f/4096.f);
    k_corr<<<4096,64,0,stream>>>(W+F_RBUFA, W+F_RBUFB, W+PRMFA, W+PRMFB, cw, cb, out);
  } else {
    short* fr = (short*)(W + T_FR0);
    for (int br=0; br<2; ++br) {
      const float* xin  = br ? tpl : x;
      float* prm1 = W + (br ? PRM1B : PRM1A);
      float* prm2 = W + (br ? PRM2B : PRM2A);
      float* sig  = W + T_SIG;
      float* fft  = W + T_FFT;
      float* rbuf = W + (br ? T_RBUFB : T_RBUFA);
      k_conv1_stats<<<256,256,0,stream>>>(xin, w1, b1, W+P1P);
      k_reduce_finalize<<<16,256,0,stream>>>(W+P1P, 256, 16, g1, bb1, prm1, 1.f/524288.f);
      k_conv2<<<4096,256,0,stream>>>(xin, w1, b1, prm1, p1, w2, b2, sig, W+P2P);
      k_reduce_finalize<<<32,256,0,stream>>>(W+P2P, 4096, 32, g2, bb2, prm2, 1.f/245760.f);
      k_sigfft<<<8192,256,0,stream>>>(sig, fft, prm2, p2, W+CTAB);
      k_xfrag2<<<7680,256,0,stream>>>(sig, fft, fr);
      k_lstm8<<<dim3(512,2,1),64,0,stream>>>(fr, fr, rbuf, rbuf,
          wihf,whhf,bihf,bhhf, wihr,whhr,bihr,bhhr);
    }
    k_bnfstats<<<dim3(15,16),256,0,stream>>>(W+T_RBUFA, W+ACCFA);
    k_bnfstats<<<dim3(15,16),256,0,stream>>>(W+T_RBUFB, W+ACCFB);
    k_finalize_bn<<<15,256,0,stream>>>(W+ACCFA, gf, bf, W+PRMFA, 3840, 1.f/4096.f);
    k_finalize_bn<<<15,256,0,stream>>>(W+ACCFB, gf, bf, W+PRMFB, 3840, 1.f/4096.f);
    k_corr<<<4096,64,0,stream>>>(W+T_RBUFA, W+T_RBUFB, W+PRMFA, W+PRMFB, cw, cb, out);
  }
}